// Round 5
// baseline (811.790 us; speedup 1.0000x reference)
//
#include <hip/hip_runtime.h>
#include <hip/hip_bf16.h>

typedef __bf16 bf16;
typedef __bf16 bf16x4 __attribute__((ext_vector_type(4)));
typedef __bf16 bf16x8 __attribute__((ext_vector_type(8)));
typedef float  f32x4  __attribute__((ext_vector_type(4)));

__device__ __forceinline__ float sigf(float x) { return 1.f / (1.f + __expf(-x)); }
// tanh(x) = 1 - 2/(e^{2x}+1): safe at both infinities (no inf/inf NaN)
__device__ __forceinline__ float tanhf_fast(float x) { return 1.f - 2.f / (1.f + __expf(2.f * x)); }

// ---------------------------------------------------------------------------
// W_eff[d][n] = sum_m W_gnn[d][m] * A[m][n]; A is I + symmetric 9-pt stencil,
// values read from the real A input (only the sparsity pattern is assumed).
// ---------------------------------------------------------------------------
__global__ __launch_bounds__(256) void k_weff(const float* __restrict__ A,
                                              const float* __restrict__ Wg,
                                              bf16* __restrict__ Weff) {
    int n = blockIdx.x * 256 + threadIdx.x;
    const int offs[9] = {0, -1, 1, 64, -64, 63, 65, -65, -63};
    float w[9];
    int   m[9];
#pragma unroll
    for (int j = 0; j < 9; j++) {
        int mm = n + offs[j];
        bool ok = (mm >= 0 && mm < 4096);
        m[j] = ok ? mm : 0;
        w[j] = ok ? A[(size_t)n * 4096 + mm] : 0.f;
    }
    int d0 = blockIdx.y * 64;
    for (int d = d0; d < d0 + 64; d++) {
        const float* wr = Wg + (size_t)d * 4096;
        float acc = 0.f;
#pragma unroll
        for (int j = 0; j < 9; j++) acc += w[j] * wr[m[j]];
        Weff[(size_t)d * 4096 + n] = (bf16)acc;
    }
}

__global__ __launch_bounds__(256) void k_conv(const float* __restrict__ a,
                                              bf16* __restrict__ o, int ntot) {
    int i = blockIdx.x * 256 + threadIdx.x;
    if (i < ntot) o[i] = (bf16)a[i];
}

// ---------------------------------------------------------------------------
// Pack W [768,256] f32 into per-wave MFMA B-fragment order, bf16:
// flat frag id fl = ((wv*6 + c)*8 + kt)*64 + lane, 8 elems each.
// Gives fully-coalesced 16 B/lane streaming loads in the GRU kernels.
// ---------------------------------------------------------------------------
__global__ __launch_bounds__(256) void k_packW(const float* __restrict__ W,
                                               bf16* __restrict__ out) {
    int fl = blockIdx.x * 256 + threadIdx.x;      // 0 .. 24575
    int lane = fl & 63;
    int kt = (fl >> 6) & 7;
    int c  = (fl >> 9) % 6;
    int wv = (fl >> 9) / 6;
    int l16 = lane & 15, q = lane >> 4;
    int g = c >> 1;
    int wr = g * 256 + wv * 32 + (c & 1) * 16 + l16;
    const float* p = W + (size_t)wr * 256 + kt * 32 + q * 8;
    float4 f0 = *(const float4*)p, f1 = *(const float4*)(p + 4);
    bf16x8 v;
    v[0] = (bf16)f0.x; v[1] = (bf16)f0.y; v[2] = (bf16)f0.z; v[3] = (bf16)f0.w;
    v[4] = (bf16)f1.x; v[5] = (bf16)f1.y; v[6] = (bf16)f1.z; v[7] = (bf16)f1.w;
    *(bf16x8*)(out + (size_t)fl * 8) = v;
}

// ---------------------------------------------------------------------------
// GEMM: C = act(A[M,K] @ B[NTOT,K]^T + bias).  Block tile 64x256, 4 waves,
// wave-tile 64x64.  ACT: 0 = +bias f32 out; 1 = +bias sigmoid bf16 out.
// ---------------------------------------------------------------------------
template <int K, int NTOT, int ACT, bool AF32>
__global__ __launch_bounds__(256) void k_gemm(const void* __restrict__ Ap,
                                              const bf16* __restrict__ Bp,
                                              const float* __restrict__ bias,
                                              void* __restrict__ Cp) {
    __shared__ bf16 sA[64 * 40];
    __shared__ bf16 sB[256 * 40];
    const int tid = threadIdx.x;
    const int lane = tid & 63, wv = tid >> 6;
    const int l16 = lane & 15, q = lane >> 4;
    const int row0 = blockIdx.x * 64;
    const int col0 = blockIdx.y * 256;
    const int ar = tid >> 2, ak = (tid & 3) * 8;

    f32x4 acc[4][4] = {};
    float4 pa0, pa1;
    bf16x8 pab;
    bf16x8 pb[4];

    auto loadA = [&](int k0) {
        if (AF32) {
            const float* p = (const float*)Ap + (size_t)(row0 + ar) * K + k0 + ak;
            pa0 = *(const float4*)p;
            pa1 = *(const float4*)(p + 4);
        } else {
            const bf16* p = (const bf16*)Ap + (size_t)(row0 + ar) * K + k0 + ak;
            pab = *(const bf16x8*)p;
        }
    };
    auto loadB = [&](int k0) {
#pragma unroll
        for (int i = 0; i < 4; i++) {
            int idx = tid + i * 256;
            int r = idx >> 2, kk = (idx & 3) * 8;
            pb[i] = *(const bf16x8*)(Bp + (size_t)(col0 + r) * K + k0 + kk);
        }
    };
    auto stage = [&]() {
        if (AF32) {
            bf16x8 v;
            v[0] = (bf16)pa0.x; v[1] = (bf16)pa0.y; v[2] = (bf16)pa0.z; v[3] = (bf16)pa0.w;
            v[4] = (bf16)pa1.x; v[5] = (bf16)pa1.y; v[6] = (bf16)pa1.z; v[7] = (bf16)pa1.w;
            *(bf16x8*)(sA + ar * 40 + ak) = v;
        } else {
            *(bf16x8*)(sA + ar * 40 + ak) = pab;
        }
#pragma unroll
        for (int i = 0; i < 4; i++) {
            int idx = tid + i * 256;
            int r = idx >> 2, kk = (idx & 3) * 8;
            *(bf16x8*)(sB + r * 40 + kk) = pb[i];
        }
    };

    loadA(0);
    loadB(0);
    const int S = K / 32;
    for (int s = 0; s < S; s++) {
        stage();
        __syncthreads();
        if (s + 1 < S) { loadA((s + 1) * 32); loadB((s + 1) * 32); }
        bf16x8 af[4], bfr[4];
#pragma unroll
        for (int tm = 0; tm < 4; tm++)
            af[tm] = *(bf16x8*)(sA + (tm * 16 + l16) * 40 + q * 8);
#pragma unroll
        for (int tn = 0; tn < 4; tn++)
            bfr[tn] = *(bf16x8*)(sB + (wv * 64 + tn * 16 + l16) * 40 + q * 8);
#pragma unroll
        for (int tm = 0; tm < 4; tm++)
#pragma unroll
            for (int tn = 0; tn < 4; tn++)
                acc[tm][tn] = __builtin_amdgcn_mfma_f32_16x16x32_bf16(
                    af[tm], bfr[tn], acc[tm][tn], 0, 0, 0);
        __syncthreads();
    }

#pragma unroll
    for (int tm = 0; tm < 4; tm++)
#pragma unroll
        for (int tn = 0; tn < 4; tn++)
#pragma unroll
            for (int r = 0; r < 4; r++) {
                int row = row0 + tm * 16 + q * 4 + r;
                int col = col0 + wv * 64 + tn * 16 + l16;
                float v = acc[tm][tn][r] + bias[col];
                if (ACT == 1)
                    ((bf16*)Cp)[(size_t)row * NTOT + col] = (bf16)sigf(v);
                else
                    ((float*)Cp)[(size_t)row * NTOT + col] = v;
            }
}

// ---------------------------------------------------------------------------
// Split-K GEMM for the K=4096 x-layer: grid (192, KS), each block computes a
// 64x256 fp32 partial over its 1024-K chunk into Cpart[ks]. 768 blocks ->
// 3 blocks/CU so barrier drains overlap across blocks.
// ---------------------------------------------------------------------------
template <int K, int CHUNK>
__global__ __launch_bounds__(256) void k_gemm_sk(const float* __restrict__ Ap,
                                                 const bf16* __restrict__ Bp,
                                                 float* __restrict__ Cpart) {
    __shared__ bf16 sA[64 * 40];
    __shared__ bf16 sB[256 * 40];
    const int tid = threadIdx.x;
    const int lane = tid & 63, wv = tid >> 6;
    const int l16 = lane & 15, q = lane >> 4;
    const int row0 = blockIdx.x * 64;
    const int kb = blockIdx.y * CHUNK;
    float* Cp = Cpart + (size_t)blockIdx.y * 12288 * 256;
    const int ar = tid >> 2, ak = (tid & 3) * 8;

    f32x4 acc[4][4] = {};
    float4 pa0, pa1;
    bf16x8 pb[4];

    auto loadA = [&](int k0) {
        const float* p = Ap + (size_t)(row0 + ar) * K + kb + k0 + ak;
        pa0 = *(const float4*)p;
        pa1 = *(const float4*)(p + 4);
    };
    auto loadB = [&](int k0) {
#pragma unroll
        for (int i = 0; i < 4; i++) {
            int idx = tid + i * 256;
            int r = idx >> 2, kk = (idx & 3) * 8;
            pb[i] = *(const bf16x8*)(Bp + (size_t)r * K + kb + k0 + kk);
        }
    };
    auto stage = [&]() {
        bf16x8 v;
        v[0] = (bf16)pa0.x; v[1] = (bf16)pa0.y; v[2] = (bf16)pa0.z; v[3] = (bf16)pa0.w;
        v[4] = (bf16)pa1.x; v[5] = (bf16)pa1.y; v[6] = (bf16)pa1.z; v[7] = (bf16)pa1.w;
        *(bf16x8*)(sA + ar * 40 + ak) = v;
#pragma unroll
        for (int i = 0; i < 4; i++) {
            int idx = tid + i * 256;
            int r = idx >> 2, kk = (idx & 3) * 8;
            *(bf16x8*)(sB + r * 40 + kk) = pb[i];
        }
    };

    loadA(0);
    loadB(0);
    const int S = CHUNK / 32;
    for (int s = 0; s < S; s++) {
        stage();
        __syncthreads();
        if (s + 1 < S) { loadA((s + 1) * 32); loadB((s + 1) * 32); }
        bf16x8 af[4], bfr[4];
#pragma unroll
        for (int tm = 0; tm < 4; tm++)
            af[tm] = *(bf16x8*)(sA + (tm * 16 + l16) * 40 + q * 8);
#pragma unroll
        for (int tn = 0; tn < 4; tn++)
            bfr[tn] = *(bf16x8*)(sB + (wv * 64 + tn * 16 + l16) * 40 + q * 8);
#pragma unroll
        for (int tm = 0; tm < 4; tm++)
#pragma unroll
            for (int tn = 0; tn < 4; tn++)
                acc[tm][tn] = __builtin_amdgcn_mfma_f32_16x16x32_bf16(
                    af[tm], bfr[tn], acc[tm][tn], 0, 0, 0);
        __syncthreads();
    }

#pragma unroll
    for (int tm = 0; tm < 4; tm++)
#pragma unroll
        for (int tn = 0; tn < 4; tn++)
#pragma unroll
            for (int r = 0; r < 4; r++) {
                int row = row0 + tm * 16 + q * 4 + r;
                int col = wv * 64 + tn * 16 + l16;
                Cp[(size_t)row * 256 + col] = acc[tm][tn][r];
            }
}

// Reduce the 4 split-K partials + bias + sigmoid -> bf16 t2.
__global__ __launch_bounds__(256) void k_reduce(const float* __restrict__ Cpart,
                                                const float* __restrict__ bias,
                                                bf16* __restrict__ t2) {
    const size_t STRIDE = (size_t)12288 * 256;
    size_t i = ((size_t)blockIdx.x * 256 + threadIdx.x) * 4;
    f32x4 s = *(const f32x4*)(Cpart + i);
#pragma unroll
    for (int ks = 1; ks < 4; ks++) {
        f32x4 p = *(const f32x4*)(Cpart + ks * STRIDE + i);
        s[0] += p[0]; s[1] += p[1]; s[2] += p[2]; s[3] += p[3];
    }
    int col = (int)(i & 255);
    const float4 b = *(const float4*)(bias + col);
    bf16x4 o;
    o[0] = (bf16)sigf(s[0] + b.x);
    o[1] = (bf16)sigf(s[1] + b.y);
    o[2] = (bf16)sigf(s[2] + b.z);
    o[3] = (bf16)sigf(s[3] + b.w);
    *(bf16x4*)(t2 + i) = o;
}

// ---------------------------------------------------------------------------
// Persistent GRU layer 0 (R0-proven, fits 128 VGPR): Whh fragments streamed
// from the pre-packed bf16 layout with a one-ktile register double buffer;
// h state fp32 in registers; bf16 copy in LDS each step. xw read in epilogue.
// ---------------------------------------------------------------------------
__global__ __launch_bounds__(512, 2) void k_gru(const float* __restrict__ xw,   // [12,1024,768]
                                                const bf16* __restrict__ Wpk,   // packed [8][6][8][64][8]
                                                const float* __restrict__ bhh,  // [768]
                                                const float* __restrict__ h0,   // [1024,256]
                                                bf16* __restrict__ hs_out,      // [12,1024,256] or null
                                                float* __restrict__ hfin) {     // [1024,256] or null
    __shared__ bf16 hl[16 * 264];
    const int tid = threadIdx.x, lane = tid & 63, wv = tid >> 6;
    const int l16 = lane & 15, q = lane >> 4;
    const int row0 = blockIdx.x * 16;
    const bf16* wb = Wpk + (size_t)wv * 6 * 8 * 64 * 8;

    float bh[6];
#pragma unroll
    for (int c = 0; c < 6; c++) {
        int g = c >> 1;
        bh[c] = bhh[g * 256 + wv * 32 + (c & 1) * 16 + l16];
    }
    float hreg[2][4];
#pragma unroll
    for (int hc = 0; hc < 2; hc++)
#pragma unroll
        for (int r = 0; r < 4; r++) {
            int row = q * 4 + r, col = wv * 32 + hc * 16 + l16;
            float h = h0[(size_t)(row0 + row) * 256 + col];
            hreg[hc][r] = h;
            hl[row * 264 + col] = (bf16)h;
        }
    __syncthreads();

    for (int t = 0; t < 12; t++) {
        f32x4 acc[6] = {};
        bf16x8 bc[6], bn[6];
#pragma unroll
        for (int c = 0; c < 6; c++)
            bc[c] = *(const bf16x8*)(wb + ((size_t)(c * 8 + 0) * 64 + lane) * 8);
#pragma unroll
        for (int kt = 0; kt < 8; kt++) {
            bf16x8 a = *(bf16x8*)(hl + l16 * 264 + kt * 32 + q * 8);
            if (kt < 7) {
#pragma unroll
                for (int c = 0; c < 6; c++)
                    bn[c] = *(const bf16x8*)(wb + ((size_t)(c * 8 + kt + 1) * 64 + lane) * 8);
            }
#pragma unroll
            for (int c = 0; c < 6; c++)
                acc[c] = __builtin_amdgcn_mfma_f32_16x16x32_bf16(a, bc[c], acc[c], 0, 0, 0);
#pragma unroll
            for (int c = 0; c < 6; c++) bc[c] = bn[c];
        }
        __syncthreads();   // all reads of hl done before overwrite
#pragma unroll
        for (int hc = 0; hc < 2; hc++)
#pragma unroll
            for (int r = 0; r < 4; r++) {
                int row = q * 4 + r, col = wv * 32 + hc * 16 + l16;
                const float* xb = xw + ((size_t)t * 1024 + row0 + row) * 768 + col;
                float rv = sigf(xb[0] + acc[hc][r] + bh[hc]);
                float zv = sigf(xb[256] + acc[2 + hc][r] + bh[2 + hc]);
                float nv = tanhf_fast(xb[512] + rv * (acc[4 + hc][r] + bh[4 + hc]));
                float hn = (1.f - zv) * nv + zv * hreg[hc][r];
                hreg[hc][r] = hn;
                bf16 hb = (bf16)hn;
                hl[row * 264 + col] = hb;
                if (hs_out) hs_out[((size_t)t * 1024 + row0 + row) * 256 + col] = hb;
            }
        __syncthreads();
    }
    if (hfin) {
#pragma unroll
        for (int hc = 0; hc < 2; hc++)
#pragma unroll
            for (int r = 0; r < 4; r++) {
                int row = q * 4 + r, col = wv * 32 + hc * 16 + l16;
                hfin[(size_t)(row0 + row) * 256 + col] = hreg[hc][r];
            }
    }
}

// ---------------------------------------------------------------------------
// GRU layer 1 with fused in-MFMA xW1 projection, v2 (anti-spill).
// R4 spilled ~1.5 KB/thread (WRITE_SIZE 50 MB vs 1 MB algorithmic): the
// 48-reg weight double-buffer + 32 acc + persist exceeded the 128-VGPR
// allocation. Fix: each pass is TWO 3-chunk sub-passes, so the weight
// buffer is bc[3]+bn[3] = 24 regs (peak live ~95-100). Costs 16 extra
// ds_read_b128/step (A-fragments read twice per pass) -- negligible.
// Per step t:
//   load   : hs[t] tile -> hv regs (issued first, hides under Pass H)
//   H-a/H-b: accRZ[0..3], accHN = h1_{t-1} @ Whh1^T   (reads h1l)
//   stage  : hv -> h0l; barrier
//   P-a/P-b: accRZ += hs[t] @ Wih1^T (r,z), accPN     (reads h0l)
//   Epi    : h1_t = GRU cell -> h1l; barrier
// ---------------------------------------------------------------------------
__global__ __launch_bounds__(512, 2) void k_gru1x(const bf16* __restrict__ hs,    // [12,1024,256]
                                                  const bf16* __restrict__ Wi1,   // packed Wih1
                                                  const bf16* __restrict__ Wh1,   // packed Whh1
                                                  const float* __restrict__ bih1, // [768]
                                                  const float* __restrict__ bhh1, // [768]
                                                  const float* __restrict__ h0l1, // [1024,256] layer-1 h0
                                                  float* __restrict__ hfin) {     // [1024,256]
    __shared__ bf16 h0l[16 * 264];
    __shared__ bf16 h1l[16 * 264];
    const int tid = threadIdx.x, lane = tid & 63, wv = tid >> 6;
    const int l16 = lane & 15, q = lane >> 4;
    const int row0 = blockIdx.x * 16;
    const bf16* wbi = Wi1 + (size_t)wv * 6 * 8 * 64 * 8;
    const bf16* wb1 = Wh1 + (size_t)wv * 6 * 8 * 64 * 8;
    // stage indices: 512 threads x bf16x8 = 16 rows x 256 cols
    const int srr = tid >> 5, scc = (tid & 31) * 8;

    float brz1[4];           // (bih1+bhh1) for r,z
    float bn1i[2], bn1h[2];  // n-gate biases, input/hidden kept apart
#pragma unroll
    for (int c = 0; c < 4; c++) {
        int col = (c >> 1) * 256 + wv * 32 + (c & 1) * 16 + l16;
        brz1[c] = bih1[col] + bhh1[col];
    }
#pragma unroll
    for (int hc = 0; hc < 2; hc++) {
        int col = 512 + wv * 32 + hc * 16 + l16;
        bn1i[hc] = bih1[col];
        bn1h[hc] = bhh1[col];
    }
    float h1r[2][4];
#pragma unroll
    for (int hc = 0; hc < 2; hc++)
#pragma unroll
        for (int r = 0; r < 4; r++) {
            int row = q * 4 + r, col = wv * 32 + hc * 16 + l16;
            float b = h0l1[(size_t)(row0 + row) * 256 + col];
            h1r[hc][r] = b;
            h1l[row * 264 + col] = (bf16)b;
        }
    __syncthreads();

    // 3-chunk weight-streaming MFMA sub-pass: chunks c0..c0+2 of wbase
    // contracted against A-fragments from hsrc, into A0/A1/A2.
    auto pass3 = [&](const bf16* hsrc, const bf16* wbase, int c0,
                     f32x4& A0, f32x4& A1, f32x4& A2) {
        bf16x8 bc[3], bn[3];
#pragma unroll
        for (int c = 0; c < 3; c++)
            bc[c] = *(const bf16x8*)(wbase + ((size_t)((c0 + c) * 8 + 0) * 64 + lane) * 8);
#pragma unroll
        for (int kt = 0; kt < 8; kt++) {
            bf16x8 a = *(const bf16x8*)(hsrc + l16 * 264 + kt * 32 + q * 8);
            if (kt < 7) {
#pragma unroll
                for (int c = 0; c < 3; c++)
                    bn[c] = *(const bf16x8*)(wbase + ((size_t)((c0 + c) * 8 + kt + 1) * 64 + lane) * 8);
            }
            A0 = __builtin_amdgcn_mfma_f32_16x16x32_bf16(a, bc[0], A0, 0, 0, 0);
            A1 = __builtin_amdgcn_mfma_f32_16x16x32_bf16(a, bc[1], A1, 0, 0, 0);
            A2 = __builtin_amdgcn_mfma_f32_16x16x32_bf16(a, bc[2], A2, 0, 0, 0);
#pragma unroll
            for (int c = 0; c < 3; c++) bc[c] = bn[c];
        }
    };

    for (int t = 0; t < 12; t++) {
        // issue hs[t] tile load early; latency hides under Pass H
        bf16x8 hv = *(const bf16x8*)(hs + ((size_t)t * 1024 + row0 + srr) * 256 + scc);
        f32x4 accRZ[4] = {}, accHN[2] = {}, accPN[2] = {};
        // ---- Pass H: hh1 = h1_{t-1} @ Whh1^T (two 3-chunk sub-passes) ----
        pass3(h1l, wb1, 0, accRZ[0], accRZ[1], accRZ[2]);
        pass3(h1l, wb1, 3, accRZ[3], accHN[0], accHN[1]);
        // stage hs[t] -> h0l (prev step's readers passed the end-of-step barrier)
        *(bf16x8*)(h0l + srr * 264 + scc) = hv;
        __syncthreads();   // h0l staged; all Pass-H reads of h1l complete
        // ---- Pass P: proj = hs[t] @ Wih1^T (r,z accumulate into accRZ) ----
        pass3(h0l, wbi, 0, accRZ[0], accRZ[1], accRZ[2]);
        pass3(h0l, wbi, 3, accRZ[3], accPN[0], accPN[1]);
        // ---- Epilogue: h1_t ----
#pragma unroll
        for (int hc = 0; hc < 2; hc++)
#pragma unroll
            for (int r = 0; r < 4; r++) {
                int row = q * 4 + r, col = wv * 32 + hc * 16 + l16;
                float rv = sigf(accRZ[hc][r] + brz1[hc]);
                float zv = sigf(accRZ[2 + hc][r] + brz1[2 + hc]);
                float nv = tanhf_fast(accPN[hc][r] + bn1i[hc]
                                      + rv * (accHN[hc][r] + bn1h[hc]));
                float hn = (1.f - zv) * nv + zv * h1r[hc][r];
                h1r[hc][r] = hn;
                if (t < 11) h1l[row * 264 + col] = (bf16)hn;
            }
        __syncthreads();   // h1_t visible before next Pass H; h0l free to restage
    }
#pragma unroll
    for (int hc = 0; hc < 2; hc++)
#pragma unroll
        for (int r = 0; r < 4; r++) {
            int row = q * 4 + r, col = wv * 32 + hc * 16 + l16;
            hfin[(size_t)(row0 + row) * 256 + col] = h1r[hc][r];
        }
}

// ---------------------------------------------------------------------------
// Final MLP on last hidden state: 256 -> 16 -> 16 -> 1, all sigmoid.
// ---------------------------------------------------------------------------
__global__ __launch_bounds__(256) void k_final(const float* __restrict__ h,
                                               const float* __restrict__ Wf0, const float* __restrict__ bf0,
                                               const float* __restrict__ Wf1, const float* __restrict__ bf1,
                                               const float* __restrict__ Wf2, const float* __restrict__ bf2,
                                               float* __restrict__ out) {
    __shared__ float sh[16 * 257];
    __shared__ float sy0[16 * 17];
    __shared__ float sy1[16 * 17];
    int tid = threadIdx.x;
    int r0 = blockIdx.x * 16;
#pragma unroll
    for (int i = 0; i < 16; i++) {
        int idx = tid + i * 256;
        int rr = idx >> 8, cc = idx & 255;
        sh[rr * 257 + cc] = h[(size_t)(r0 + rr) * 256 + cc];
    }
    __syncthreads();
    int rl = tid >> 4, j = tid & 15;
    float acc = bf0[j];
    for (int k = 0; k < 256; k++) acc += sh[rl * 257 + k] * Wf0[j * 256 + k];
    sy0[rl * 17 + j] = sigf(acc);
    __syncthreads();
    float acc1 = bf1[j];
#pragma unroll
    for (int k = 0; k < 16; k++) acc1 += sy0[rl * 17 + k] * Wf1[j * 16 + k];
    sy1[rl * 17 + j] = sigf(acc1);
    __syncthreads();
    if (tid < 16) {
        float a2 = bf2[0];
#pragma unroll
        for (int k = 0; k < 16; k++) a2 += sy1[tid * 17 + k] * Wf2[k];
        out[r0 + tid] = sigf(a2);
    }
}

extern "C" void kernel_launch(void* const* d_in, const int* in_sizes, int n_in,
                              void* d_out, int out_size, void* d_ws, size_t ws_size,
                              hipStream_t stream) {
    const float* x    = (const float*)d_in[0];
    const float* h0   = (const float*)d_in[1];
    const float* A    = (const float*)d_in[2];
    const float* Wgnn = (const float*)d_in[3];
    const float* bgnn = (const float*)d_in[4];
    const float* Wlin = (const float*)d_in[5];
    const float* blin = (const float*)d_in[6];
    const float* Wih0 = (const float*)d_in[7];
    const float* Whh0 = (const float*)d_in[8];
    const float* bih0 = (const float*)d_in[9];
    const float* bhh0 = (const float*)d_in[10];
    const float* Wih1 = (const float*)d_in[11];
    const float* Whh1 = (const float*)d_in[12];
    const float* bih1 = (const float*)d_in[13];
    const float* bhh1 = (const float*)d_in[14];
    const float* Wf0  = (const float*)d_in[15];
    const float* bf0  = (const float*)d_in[16];
    const float* Wf1  = (const float*)d_in[17];
    const float* bf1  = (const float*)d_in[18];
    const float* Wf2  = (const float*)d_in[19];
    const float* bf2  = (const float*)d_in[20];
    float* out = (float*)d_out;

    char* w = (char*)d_ws;
    bf16* Weff  = (bf16*)w;  w += (size_t)256 * 4096 * 2;
    bf16* WlinB = (bf16*)w;  w += (size_t)256 * 256 * 2;
    bf16* Wih0B = (bf16*)w;  w += (size_t)768 * 256 * 2;
    bf16* Wpk0  = (bf16*)w;  w += (size_t)768 * 256 * 2;
    bf16* Wpk1  = (bf16*)w;  w += (size_t)768 * 256 * 2;
    bf16* Wpki1 = (bf16*)w;  w += (size_t)768 * 256 * 2;
    bf16* t2    = (bf16*)w;  w += (size_t)12288 * 256 * 2;
    bf16* t4    = (bf16*)w;  w += (size_t)12288 * 256 * 2;
    // Union region: Cpart (4 x 12288 x 256 f32 = 50.3 MB) is dead before
    // xwb/hs/hfin are first written (xwb 37.7 + hs 6.3 + hfin 1.0 = 45 MB).
    float* Cpart = (float*)w;
    float* xwb  = (float*)w;
    bf16*  hs   = (bf16*)(w + (size_t)12288 * 768 * 4);
    float* hfin = (float*)(w + (size_t)12288 * 768 * 4 + (size_t)12288 * 256 * 2);
    w += (size_t)4 * 12288 * 256 * 4;
    (void)ws_size;

    k_weff<<<dim3(16, 4), 256, 0, stream>>>(A, Wgnn, Weff);
    k_conv<<<dim3(256), 256, 0, stream>>>(Wlin, WlinB, 256 * 256);
    k_conv<<<dim3(768), 256, 0, stream>>>(Wih0, Wih0B, 768 * 256);
    k_packW<<<dim3(96), 256, 0, stream>>>(Whh0, Wpk0);
    k_packW<<<dim3(96), 256, 0, stream>>>(Whh1, Wpk1);
    k_packW<<<dim3(96), 256, 0, stream>>>(Wih1, Wpki1);

    // t2 = sigmoid(x @ Weff^T + b_gnn): M=12288, K=4096 split 4 ways
    k_gemm_sk<4096, 1024><<<dim3(192, 4), 256, 0, stream>>>(x, Weff, Cpart);
    k_reduce<<<dim3(3072), 256, 0, stream>>>(Cpart, bgnn, t2);
    // t4 = sigmoid(t2 @ Wlin^T + b_lin)
    k_gemm<256, 256, 1, false><<<dim3(192, 1), 256, 0, stream>>>(t2, WlinB, blin, t4);
    // xW0 = t4 @ Wih0^T + bih0  -> [12288, 768] f32
    k_gemm<256, 768, 0, false><<<dim3(192, 3), 256, 0, stream>>>(t4, Wih0B, bih0, xwb);
    // GRU layer 0 -> hs (bf16, all timesteps)
    k_gru<<<dim3(64), 512, 0, stream>>>(xwb, Wpk0, bhh0, h0, hs, nullptr);
    // GRU layer 1 with fused xW1 projection -> final hidden only
    k_gru1x<<<dim3(64), 512, 0, stream>>>(hs, Wpki1, Wpk1, bih1, bhh1,
                                          h0 + (size_t)1024 * 256, hfin);
    // final MLP
    k_final<<<dim3(64), 256, 0, stream>>>(hfin, Wf0, bf0, Wf1, bf1, Wf2, bf2, out);
}

// Round 6
// 657.055 us; speedup vs baseline: 1.2355x; 1.2355x over previous
//
#include <hip/hip_runtime.h>
#include <hip/hip_bf16.h>

typedef __bf16 bf16;
typedef __bf16 bf16x4 __attribute__((ext_vector_type(4)));
typedef __bf16 bf16x8 __attribute__((ext_vector_type(8)));
typedef float  f32x4  __attribute__((ext_vector_type(4)));

__device__ __forceinline__ float sigf(float x) { return 1.f / (1.f + __expf(-x)); }
// tanh(x) = 1 - 2/(e^{2x}+1): safe at both infinities (no inf/inf NaN)
__device__ __forceinline__ float tanhf_fast(float x) { return 1.f - 2.f / (1.f + __expf(2.f * x)); }

// ---------------------------------------------------------------------------
// NOTE (R1-R5 journal): all attempts to fuse the xW1 projection into a GRU
// kernel (monolithic or split) produced ~50 MB/dispatch of phantom HBM
// read+write traffic (accumulator/scratch round-trips the register dieting
// in R2/R3/R5 could not remove; VGPR alloc pinned at 128 even with
// launch_bounds slack in R2). Every fused variant lost to the R0 split
// structure (791/811/997 vs 663.8 us). This file is the R0 structure with
// one safe change: the 5 tiny prologue dispatches merged into k_prep.
// ---------------------------------------------------------------------------

// ---------------------------------------------------------------------------
// W_eff[d][n] = sum_m W_gnn[d][m] * A[m][n]; A is I + symmetric 9-pt stencil,
// values read from the real A input (only the sparsity pattern is assumed).
// ---------------------------------------------------------------------------
__global__ __launch_bounds__(256) void k_weff(const float* __restrict__ A,
                                              const float* __restrict__ Wg,
                                              bf16* __restrict__ Weff) {
    int n = blockIdx.x * 256 + threadIdx.x;
    const int offs[9] = {0, -1, 1, 64, -64, 63, 65, -65, -63};
    float w[9];
    int   m[9];
#pragma unroll
    for (int j = 0; j < 9; j++) {
        int mm = n + offs[j];
        bool ok = (mm >= 0 && mm < 4096);
        m[j] = ok ? mm : 0;
        w[j] = ok ? A[(size_t)n * 4096 + mm] : 0.f;
    }
    int d0 = blockIdx.y * 64;
    for (int d = d0; d < d0 + 64; d++) {
        const float* wr = Wg + (size_t)d * 4096;
        float acc = 0.f;
#pragma unroll
        for (int j = 0; j < 9; j++) acc += w[j] * wr[m[j]];
        Weff[(size_t)d * 4096 + n] = (bf16)acc;
    }
}

// ---------------------------------------------------------------------------
// Merged prologue: 3 f32->bf16 weight conversions + 2 MFMA-order packs in a
// single dispatch (range dispatch on blockIdx.x). Per-block work identical
// to the old k_conv/k_packW; saves 4 launch+drain slots on the serial stream.
// Pack layout: flat frag id fl = ((wv*6 + c)*8 + kt)*64 + lane, 8 elems each.
// ---------------------------------------------------------------------------
__device__ __forceinline__ void prep_conv(const float* __restrict__ a,
                                          bf16* __restrict__ o, int blk) {
    int i = blk * 256 + threadIdx.x;
    o[i] = (bf16)a[i];
}

__device__ __forceinline__ void prep_pack(const float* __restrict__ W,
                                          bf16* __restrict__ out, int blk) {
    int fl = blk * 256 + threadIdx.x;             // 0 .. 24575
    int lane = fl & 63;
    int kt = (fl >> 6) & 7;
    int c  = (fl >> 9) % 6;
    int wv = (fl >> 9) / 6;
    int l16 = lane & 15, q = lane >> 4;
    int g = c >> 1;
    int wr = g * 256 + wv * 32 + (c & 1) * 16 + l16;
    const float* p = W + (size_t)wr * 256 + kt * 32 + q * 8;
    float4 f0 = *(const float4*)p, f1 = *(const float4*)(p + 4);
    bf16x8 v;
    v[0] = (bf16)f0.x; v[1] = (bf16)f0.y; v[2] = (bf16)f0.z; v[3] = (bf16)f0.w;
    v[4] = (bf16)f1.x; v[5] = (bf16)f1.y; v[6] = (bf16)f1.z; v[7] = (bf16)f1.w;
    *(bf16x8*)(out + (size_t)fl * 8) = v;
}

__global__ __launch_bounds__(256) void k_prep(const float* __restrict__ Wlin, bf16* __restrict__ WlinB,
                                              const float* __restrict__ Wih0, bf16* __restrict__ Wih0B,
                                              const float* __restrict__ Wih1, bf16* __restrict__ Wih1B,
                                              const float* __restrict__ Whh0, bf16* __restrict__ Wpk0,
                                              const float* __restrict__ Whh1, bf16* __restrict__ Wpk1) {
    int b = blockIdx.x;
    if (b < 256)        prep_conv(Wlin, WlinB, b);            // 256*256   = 65536
    else if (b < 1024)  prep_conv(Wih0, Wih0B, b - 256);      // 768*256   = 196608
    else if (b < 1792)  prep_conv(Wih1, Wih1B, b - 1024);     // 768*256   = 196608
    else if (b < 1888)  prep_pack(Whh0, Wpk0, b - 1792);      // 96 blocks
    else                prep_pack(Whh1, Wpk1, b - 1888);      // 96 blocks
}

// ---------------------------------------------------------------------------
// GEMM: C = act(A[M,K] @ B[NTOT,K]^T + bias).  Block tile 64x256, 4 waves,
// wave-tile 64x64.  ACT: 0 = +bias f32 out; 1 = +bias sigmoid bf16 out.
// ---------------------------------------------------------------------------
template <int K, int NTOT, int ACT, bool AF32>
__global__ __launch_bounds__(256) void k_gemm(const void* __restrict__ Ap,
                                              const bf16* __restrict__ Bp,
                                              const float* __restrict__ bias,
                                              void* __restrict__ Cp) {
    __shared__ bf16 sA[64 * 40];
    __shared__ bf16 sB[256 * 40];
    const int tid = threadIdx.x;
    const int lane = tid & 63, wv = tid >> 6;
    const int l16 = lane & 15, q = lane >> 4;
    const int row0 = blockIdx.x * 64;
    const int col0 = blockIdx.y * 256;
    const int ar = tid >> 2, ak = (tid & 3) * 8;

    f32x4 acc[4][4] = {};
    float4 pa0, pa1;
    bf16x8 pab;
    bf16x8 pb[4];

    auto loadA = [&](int k0) {
        if (AF32) {
            const float* p = (const float*)Ap + (size_t)(row0 + ar) * K + k0 + ak;
            pa0 = *(const float4*)p;
            pa1 = *(const float4*)(p + 4);
        } else {
            const bf16* p = (const bf16*)Ap + (size_t)(row0 + ar) * K + k0 + ak;
            pab = *(const bf16x8*)p;
        }
    };
    auto loadB = [&](int k0) {
#pragma unroll
        for (int i = 0; i < 4; i++) {
            int idx = tid + i * 256;
            int r = idx >> 2, kk = (idx & 3) * 8;
            pb[i] = *(const bf16x8*)(Bp + (size_t)(col0 + r) * K + k0 + kk);
        }
    };
    auto stage = [&]() {
        if (AF32) {
            bf16x8 v;
            v[0] = (bf16)pa0.x; v[1] = (bf16)pa0.y; v[2] = (bf16)pa0.z; v[3] = (bf16)pa0.w;
            v[4] = (bf16)pa1.x; v[5] = (bf16)pa1.y; v[6] = (bf16)pa1.z; v[7] = (bf16)pa1.w;
            *(bf16x8*)(sA + ar * 40 + ak) = v;
        } else {
            *(bf16x8*)(sA + ar * 40 + ak) = pab;
        }
#pragma unroll
        for (int i = 0; i < 4; i++) {
            int idx = tid + i * 256;
            int r = idx >> 2, kk = (idx & 3) * 8;
            *(bf16x8*)(sB + r * 40 + kk) = pb[i];
        }
    };

    loadA(0);
    loadB(0);
    const int S = K / 32;
    for (int s = 0; s < S; s++) {
        stage();
        __syncthreads();
        if (s + 1 < S) { loadA((s + 1) * 32); loadB((s + 1) * 32); }
        bf16x8 af[4], bfr[4];
#pragma unroll
        for (int tm = 0; tm < 4; tm++)
            af[tm] = *(bf16x8*)(sA + (tm * 16 + l16) * 40 + q * 8);
#pragma unroll
        for (int tn = 0; tn < 4; tn++)
            bfr[tn] = *(bf16x8*)(sB + (wv * 64 + tn * 16 + l16) * 40 + q * 8);
#pragma unroll
        for (int tm = 0; tm < 4; tm++)
#pragma unroll
            for (int tn = 0; tn < 4; tn++)
                acc[tm][tn] = __builtin_amdgcn_mfma_f32_16x16x32_bf16(
                    af[tm], bfr[tn], acc[tm][tn], 0, 0, 0);
        __syncthreads();
    }

#pragma unroll
    for (int tm = 0; tm < 4; tm++)
#pragma unroll
        for (int tn = 0; tn < 4; tn++)
#pragma unroll
            for (int r = 0; r < 4; r++) {
                int row = row0 + tm * 16 + q * 4 + r;
                int col = col0 + wv * 64 + tn * 16 + l16;
                float v = acc[tm][tn][r] + bias[col];
                if (ACT == 1)
                    ((bf16*)Cp)[(size_t)row * NTOT + col] = (bf16)sigf(v);
                else
                    ((float*)Cp)[(size_t)row * NTOT + col] = v;
            }
}

// ---------------------------------------------------------------------------
// Split-K GEMM for the K=4096 x-layer: grid (192, KS), each block computes a
// 64x256 fp32 partial over its 1024-K chunk into Cpart[ks]. 768 blocks ->
// 3 blocks/CU so barrier drains overlap across blocks.
// ---------------------------------------------------------------------------
template <int K, int CHUNK>
__global__ __launch_bounds__(256) void k_gemm_sk(const float* __restrict__ Ap,
                                                 const bf16* __restrict__ Bp,
                                                 float* __restrict__ Cpart) {
    __shared__ bf16 sA[64 * 40];
    __shared__ bf16 sB[256 * 40];
    const int tid = threadIdx.x;
    const int lane = tid & 63, wv = tid >> 6;
    const int l16 = lane & 15, q = lane >> 4;
    const int row0 = blockIdx.x * 64;
    const int kb = blockIdx.y * CHUNK;
    float* Cp = Cpart + (size_t)blockIdx.y * 12288 * 256;
    const int ar = tid >> 2, ak = (tid & 3) * 8;

    f32x4 acc[4][4] = {};
    float4 pa0, pa1;
    bf16x8 pb[4];

    auto loadA = [&](int k0) {
        const float* p = Ap + (size_t)(row0 + ar) * K + kb + k0 + ak;
        pa0 = *(const float4*)p;
        pa1 = *(const float4*)(p + 4);
    };
    auto loadB = [&](int k0) {
#pragma unroll
        for (int i = 0; i < 4; i++) {
            int idx = tid + i * 256;
            int r = idx >> 2, kk = (idx & 3) * 8;
            pb[i] = *(const bf16x8*)(Bp + (size_t)r * K + kb + k0 + kk);
        }
    };
    auto stage = [&]() {
        bf16x8 v;
        v[0] = (bf16)pa0.x; v[1] = (bf16)pa0.y; v[2] = (bf16)pa0.z; v[3] = (bf16)pa0.w;
        v[4] = (bf16)pa1.x; v[5] = (bf16)pa1.y; v[6] = (bf16)pa1.z; v[7] = (bf16)pa1.w;
        *(bf16x8*)(sA + ar * 40 + ak) = v;
#pragma unroll
        for (int i = 0; i < 4; i++) {
            int idx = tid + i * 256;
            int r = idx >> 2, kk = (idx & 3) * 8;
            *(bf16x8*)(sB + r * 40 + kk) = pb[i];
        }
    };

    loadA(0);
    loadB(0);
    const int S = CHUNK / 32;
    for (int s = 0; s < S; s++) {
        stage();
        __syncthreads();
        if (s + 1 < S) { loadA((s + 1) * 32); loadB((s + 1) * 32); }
        bf16x8 af[4], bfr[4];
#pragma unroll
        for (int tm = 0; tm < 4; tm++)
            af[tm] = *(bf16x8*)(sA + (tm * 16 + l16) * 40 + q * 8);
#pragma unroll
        for (int tn = 0; tn < 4; tn++)
            bfr[tn] = *(bf16x8*)(sB + (wv * 64 + tn * 16 + l16) * 40 + q * 8);
#pragma unroll
        for (int tm = 0; tm < 4; tm++)
#pragma unroll
            for (int tn = 0; tn < 4; tn++)
                acc[tm][tn] = __builtin_amdgcn_mfma_f32_16x16x32_bf16(
                    af[tm], bfr[tn], acc[tm][tn], 0, 0, 0);
        __syncthreads();
    }

#pragma unroll
    for (int tm = 0; tm < 4; tm++)
#pragma unroll
        for (int tn = 0; tn < 4; tn++)
#pragma unroll
            for (int r = 0; r < 4; r++) {
                int row = row0 + tm * 16 + q * 4 + r;
                int col = wv * 64 + tn * 16 + l16;
                Cp[(size_t)row * 256 + col] = acc[tm][tn][r];
            }
}

// Reduce the 4 split-K partials + bias + sigmoid -> bf16 t2.
__global__ __launch_bounds__(256) void k_reduce(const float* __restrict__ Cpart,
                                                const float* __restrict__ bias,
                                                bf16* __restrict__ t2) {
    const size_t STRIDE = (size_t)12288 * 256;
    size_t i = ((size_t)blockIdx.x * 256 + threadIdx.x) * 4;
    f32x4 s = *(const f32x4*)(Cpart + i);
#pragma unroll
    for (int ks = 1; ks < 4; ks++) {
        f32x4 p = *(const f32x4*)(Cpart + ks * STRIDE + i);
        s[0] += p[0]; s[1] += p[1]; s[2] += p[2]; s[3] += p[3];
    }
    int col = (int)(i & 255);
    const float4 b = *(const float4*)(bias + col);
    bf16x4 o;
    o[0] = (bf16)sigf(s[0] + b.x);
    o[1] = (bf16)sigf(s[1] + b.y);
    o[2] = (bf16)sigf(s[2] + b.z);
    o[3] = (bf16)sigf(s[3] + b.w);
    *(bf16x4*)(t2 + i) = o;
}

// ---------------------------------------------------------------------------
// Persistent GRU layer (R0-proven, fits 128 VGPR, no phantom traffic):
// Whh fragments streamed from the pre-packed bf16 layout with a one-ktile
// register double buffer; h state fp32 in registers; bf16 copy in LDS each
// step; xw read in the epilogue.
// ---------------------------------------------------------------------------
__global__ __launch_bounds__(512, 2) void k_gru(const float* __restrict__ xw,   // [12,1024,768]
                                                const bf16* __restrict__ Wpk,   // packed [8][6][8][64][8]
                                                const float* __restrict__ bhh,  // [768]
                                                const float* __restrict__ h0,   // [1024,256]
                                                bf16* __restrict__ hs_out,      // [12,1024,256] or null
                                                float* __restrict__ hfin) {     // [1024,256] or null
    __shared__ bf16 hl[16 * 264];
    const int tid = threadIdx.x, lane = tid & 63, wv = tid >> 6;
    const int l16 = lane & 15, q = lane >> 4;
    const int row0 = blockIdx.x * 16;
    const bf16* wb = Wpk + (size_t)wv * 6 * 8 * 64 * 8;

    float bh[6];
#pragma unroll
    for (int c = 0; c < 6; c++) {
        int g = c >> 1;
        bh[c] = bhh[g * 256 + wv * 32 + (c & 1) * 16 + l16];
    }
    float hreg[2][4];
#pragma unroll
    for (int hc = 0; hc < 2; hc++)
#pragma unroll
        for (int r = 0; r < 4; r++) {
            int row = q * 4 + r, col = wv * 32 + hc * 16 + l16;
            float h = h0[(size_t)(row0 + row) * 256 + col];
            hreg[hc][r] = h;
            hl[row * 264 + col] = (bf16)h;
        }
    __syncthreads();

    for (int t = 0; t < 12; t++) {
        f32x4 acc[6] = {};
        bf16x8 bc[6], bn[6];
#pragma unroll
        for (int c = 0; c < 6; c++)
            bc[c] = *(const bf16x8*)(wb + ((size_t)(c * 8 + 0) * 64 + lane) * 8);
#pragma unroll
        for (int kt = 0; kt < 8; kt++) {
            bf16x8 a = *(bf16x8*)(hl + l16 * 264 + kt * 32 + q * 8);
            if (kt < 7) {
#pragma unroll
                for (int c = 0; c < 6; c++)
                    bn[c] = *(const bf16x8*)(wb + ((size_t)(c * 8 + kt + 1) * 64 + lane) * 8);
            }
#pragma unroll
            for (int c = 0; c < 6; c++)
                acc[c] = __builtin_amdgcn_mfma_f32_16x16x32_bf16(a, bc[c], acc[c], 0, 0, 0);
#pragma unroll
            for (int c = 0; c < 6; c++) bc[c] = bn[c];
        }
        __syncthreads();   // all reads of hl done before overwrite
#pragma unroll
        for (int hc = 0; hc < 2; hc++)
#pragma unroll
            for (int r = 0; r < 4; r++) {
                int row = q * 4 + r, col = wv * 32 + hc * 16 + l16;
                const float* xb = xw + ((size_t)t * 1024 + row0 + row) * 768 + col;
                float rv = sigf(xb[0] + acc[hc][r] + bh[hc]);
                float zv = sigf(xb[256] + acc[2 + hc][r] + bh[2 + hc]);
                float nv = tanhf_fast(xb[512] + rv * (acc[4 + hc][r] + bh[4 + hc]));
                float hn = (1.f - zv) * nv + zv * hreg[hc][r];
                hreg[hc][r] = hn;
                bf16 hb = (bf16)hn;
                hl[row * 264 + col] = hb;
                if (hs_out) hs_out[((size_t)t * 1024 + row0 + row) * 256 + col] = hb;
            }
        __syncthreads();
    }
    if (hfin) {
#pragma unroll
        for (int hc = 0; hc < 2; hc++)
#pragma unroll
            for (int r = 0; r < 4; r++) {
                int row = q * 4 + r, col = wv * 32 + hc * 16 + l16;
                hfin[(size_t)(row0 + row) * 256 + col] = hreg[hc][r];
            }
    }
}

// ---------------------------------------------------------------------------
// Final MLP on last hidden state: 256 -> 16 -> 16 -> 1, all sigmoid.
// ---------------------------------------------------------------------------
__global__ __launch_bounds__(256) void k_final(const float* __restrict__ h,
                                               const float* __restrict__ Wf0, const float* __restrict__ bf0,
                                               const float* __restrict__ Wf1, const float* __restrict__ bf1,
                                               const float* __restrict__ Wf2, const float* __restrict__ bf2,
                                               float* __restrict__ out) {
    __shared__ float sh[16 * 257];
    __shared__ float sy0[16 * 17];
    __shared__ float sy1[16 * 17];
    int tid = threadIdx.x;
    int r0 = blockIdx.x * 16;
#pragma unroll
    for (int i = 0; i < 16; i++) {
        int idx = tid + i * 256;
        int rr = idx >> 8, cc = idx & 255;
        sh[rr * 257 + cc] = h[(size_t)(r0 + rr) * 256 + cc];
    }
    __syncthreads();
    int rl = tid >> 4, j = tid & 15;
    float acc = bf0[j];
    for (int k = 0; k < 256; k++) acc += sh[rl * 257 + k] * Wf0[j * 256 + k];
    sy0[rl * 17 + j] = sigf(acc);
    __syncthreads();
    float acc1 = bf1[j];
#pragma unroll
    for (int k = 0; k < 16; k++) acc1 += sy0[rl * 17 + k] * Wf1[j * 16 + k];
    sy1[rl * 17 + j] = sigf(acc1);
    __syncthreads();
    if (tid < 16) {
        float a2 = bf2[0];
#pragma unroll
        for (int k = 0; k < 16; k++) a2 += sy1[tid * 17 + k] * Wf2[k];
        out[r0 + tid] = sigf(a2);
    }
}

extern "C" void kernel_launch(void* const* d_in, const int* in_sizes, int n_in,
                              void* d_out, int out_size, void* d_ws, size_t ws_size,
                              hipStream_t stream) {
    const float* x    = (const float*)d_in[0];
    const float* h0   = (const float*)d_in[1];
    const float* A    = (const float*)d_in[2];
    const float* Wgnn = (const float*)d_in[3];
    const float* bgnn = (const float*)d_in[4];
    const float* Wlin = (const float*)d_in[5];
    const float* blin = (const float*)d_in[6];
    const float* Wih0 = (const float*)d_in[7];
    const float* Whh0 = (const float*)d_in[8];
    const float* bih0 = (const float*)d_in[9];
    const float* bhh0 = (const float*)d_in[10];
    const float* Wih1 = (const float*)d_in[11];
    const float* Whh1 = (const float*)d_in[12];
    const float* bih1 = (const float*)d_in[13];
    const float* bhh1 = (const float*)d_in[14];
    const float* Wf0  = (const float*)d_in[15];
    const float* bf0  = (const float*)d_in[16];
    const float* Wf1  = (const float*)d_in[17];
    const float* bf1  = (const float*)d_in[18];
    const float* Wf2  = (const float*)d_in[19];
    const float* bf2  = (const float*)d_in[20];
    float* out = (float*)d_out;

    char* w = (char*)d_ws;
    bf16* Weff  = (bf16*)w;  w += (size_t)256 * 4096 * 2;
    bf16* WlinB = (bf16*)w;  w += (size_t)256 * 256 * 2;
    bf16* Wih0B = (bf16*)w;  w += (size_t)768 * 256 * 2;
    bf16* Wih1B = (bf16*)w;  w += (size_t)768 * 256 * 2;
    bf16* Wpk0  = (bf16*)w;  w += (size_t)768 * 256 * 2;
    bf16* Wpk1  = (bf16*)w;  w += (size_t)768 * 256 * 2;
    bf16* t2    = (bf16*)w;  w += (size_t)12288 * 256 * 2;
    bf16* t4    = (bf16*)w;  w += (size_t)12288 * 256 * 2;
    // Union region: Cpart (4 x 12288 x 256 f32 = 50.3 MB) is dead before
    // xwb/hs/hfin are first written (xwb 37.7 + hs 6.3 + hfin 1.0 = 45 MB).
    float* Cpart = (float*)w;
    float* xwb  = (float*)w;
    bf16*  hs   = (bf16*)(w + (size_t)12288 * 768 * 4);
    float* hfin = (float*)(w + (size_t)12288 * 768 * 4 + (size_t)12288 * 256 * 2);
    w += (size_t)4 * 12288 * 256 * 4;
    (void)ws_size;

    k_weff<<<dim3(16, 4), 256, 0, stream>>>(A, Wgnn, Weff);
    k_prep<<<dim3(1984), 256, 0, stream>>>(Wlin, WlinB, Wih0, Wih0B, Wih1, Wih1B,
                                           Whh0, Wpk0, Whh1, Wpk1);

    // t2 = sigmoid(x @ Weff^T + b_gnn): M=12288, K=4096 split 4 ways
    k_gemm_sk<4096, 1024><<<dim3(192, 4), 256, 0, stream>>>(x, Weff, Cpart);
    k_reduce<<<dim3(3072), 256, 0, stream>>>(Cpart, bgnn, t2);
    // t4 = sigmoid(t2 @ Wlin^T + b_lin)
    k_gemm<256, 256, 1, false><<<dim3(192, 1), 256, 0, stream>>>(t2, WlinB, blin, t4);
    // xW0 = t4 @ Wih0^T + bih0  -> [12288, 768] f32
    k_gemm<256, 768, 0, false><<<dim3(192, 3), 256, 0, stream>>>(t4, Wih0B, bih0, xwb);
    // GRU layer 0 -> hs (bf16, all timesteps)
    k_gru<<<dim3(64), 512, 0, stream>>>(xwb, Wpk0, bhh0, h0, hs, nullptr);
    // xW1 = hs @ Wih1^T + bih1 (reuses xwb)
    k_gemm<256, 768, 0, false><<<dim3(192, 3), 256, 0, stream>>>(hs, Wih1B, bih1, xwb);
    // GRU layer 1 -> final hidden only
    k_gru<<<dim3(64), 512, 0, stream>>>(xwb, Wpk1, bhh1, h0 + (size_t)1024 * 256, nullptr, hfin);
    // final MLP
    k_final<<<dim3(64), 256, 0, stream>>>(hfin, Wf0, bf0, Wf1, bf1, Wf2, bf2, out);
}

// Round 7
// 557.187 us; speedup vs baseline: 1.4569x; 1.1792x over previous
//
#include <hip/hip_runtime.h>
#include <hip/hip_bf16.h>

typedef __bf16 bf16;
typedef __bf16 bf16x4 __attribute__((ext_vector_type(4)));
typedef __bf16 bf16x8 __attribute__((ext_vector_type(8)));
typedef float  f32x4  __attribute__((ext_vector_type(4)));

__device__ __forceinline__ float sigf(float x) { return 1.f / (1.f + __expf(-x)); }
// tanh(x) = 1 - 2/(e^{2x}+1): safe at both infinities (no inf/inf NaN)
__device__ __forceinline__ float tanhf_fast(float x) { return 1.f - 2.f / (1.f + __expf(2.f * x)); }

// ---------------------------------------------------------------------------
// Journal (R1-R6): fusing the xW1 projection into a GRU kernel always spilled
// (~50 MB phantom HBM traffic, VGPR pinned at 128); the R0 split structure is
// the keeper. R6 = R0 + merged prologue = 657 us. R7 attacks the measured
// biggest app cost: the two k_gru dispatches (~82 us each, inferred from
// R5/R6 deltas), whose per-step critical path exposes the xw epilogue load
// latency. Fix: LDS prefetch via global_load_lds (no VGPRs held -> no spill).
// ---------------------------------------------------------------------------

// ---------------------------------------------------------------------------
// W_eff[d][n] = sum_m W_gnn[d][m] * A[m][n]; A is I + symmetric 9-pt stencil,
// values read from the real A input (only the sparsity pattern is assumed).
// R7: 8 d-values per block (was 64) -> 512 blocks, 8x more parallelism.
// ---------------------------------------------------------------------------
__global__ __launch_bounds__(256) void k_weff(const float* __restrict__ A,
                                              const float* __restrict__ Wg,
                                              bf16* __restrict__ Weff) {
    int n = blockIdx.x * 256 + threadIdx.x;
    const int offs[9] = {0, -1, 1, 64, -64, 63, 65, -65, -63};
    float w[9];
    int   m[9];
#pragma unroll
    for (int j = 0; j < 9; j++) {
        int mm = n + offs[j];
        bool ok = (mm >= 0 && mm < 4096);
        m[j] = ok ? mm : 0;
        w[j] = ok ? A[(size_t)n * 4096 + mm] : 0.f;
    }
    int d0 = blockIdx.y * 8;
    for (int d = d0; d < d0 + 8; d++) {
        const float* wr = Wg + (size_t)d * 4096;
        float acc = 0.f;
#pragma unroll
        for (int j = 0; j < 9; j++) acc += w[j] * wr[m[j]];
        Weff[(size_t)d * 4096 + n] = (bf16)acc;
    }
}

// ---------------------------------------------------------------------------
// Merged prologue: 3 f32->bf16 weight conversions + 2 MFMA-order packs in a
// single dispatch (range dispatch on blockIdx.x).
// Pack layout: flat frag id fl = ((wv*6 + c)*8 + kt)*64 + lane, 8 elems each.
// ---------------------------------------------------------------------------
__device__ __forceinline__ void prep_conv(const float* __restrict__ a,
                                          bf16* __restrict__ o, int blk) {
    int i = blk * 256 + threadIdx.x;
    o[i] = (bf16)a[i];
}

__device__ __forceinline__ void prep_pack(const float* __restrict__ W,
                                          bf16* __restrict__ out, int blk) {
    int fl = blk * 256 + threadIdx.x;             // 0 .. 24575
    int lane = fl & 63;
    int kt = (fl >> 6) & 7;
    int c  = (fl >> 9) % 6;
    int wv = (fl >> 9) / 6;
    int l16 = lane & 15, q = lane >> 4;
    int g = c >> 1;
    int wr = g * 256 + wv * 32 + (c & 1) * 16 + l16;
    const float* p = W + (size_t)wr * 256 + kt * 32 + q * 8;
    float4 f0 = *(const float4*)p, f1 = *(const float4*)(p + 4);
    bf16x8 v;
    v[0] = (bf16)f0.x; v[1] = (bf16)f0.y; v[2] = (bf16)f0.z; v[3] = (bf16)f0.w;
    v[4] = (bf16)f1.x; v[5] = (bf16)f1.y; v[6] = (bf16)f1.z; v[7] = (bf16)f1.w;
    *(bf16x8*)(out + (size_t)fl * 8) = v;
}

__global__ __launch_bounds__(256) void k_prep(const float* __restrict__ Wlin, bf16* __restrict__ WlinB,
                                              const float* __restrict__ Wih0, bf16* __restrict__ Wih0B,
                                              const float* __restrict__ Wih1, bf16* __restrict__ Wih1B,
                                              const float* __restrict__ Whh0, bf16* __restrict__ Wpk0,
                                              const float* __restrict__ Whh1, bf16* __restrict__ Wpk1) {
    int b = blockIdx.x;
    if (b < 256)        prep_conv(Wlin, WlinB, b);            // 256*256   = 65536
    else if (b < 1024)  prep_conv(Wih0, Wih0B, b - 256);      // 768*256   = 196608
    else if (b < 1792)  prep_conv(Wih1, Wih1B, b - 1024);     // 768*256   = 196608
    else if (b < 1888)  prep_pack(Whh0, Wpk0, b - 1792);      // 96 blocks
    else                prep_pack(Whh1, Wpk1, b - 1888);      // 96 blocks
}

// ---------------------------------------------------------------------------
// GEMM: C = act(A[M,K] @ B[NTOT,K]^T + bias).  Block tile 64x256, 4 waves,
// wave-tile 64x64.  ACT: 0 = +bias f32 out; 1 = +bias sigmoid bf16 out.
// ---------------------------------------------------------------------------
template <int K, int NTOT, int ACT, bool AF32>
__global__ __launch_bounds__(256) void k_gemm(const void* __restrict__ Ap,
                                              const bf16* __restrict__ Bp,
                                              const float* __restrict__ bias,
                                              void* __restrict__ Cp) {
    __shared__ bf16 sA[64 * 40];
    __shared__ bf16 sB[256 * 40];
    const int tid = threadIdx.x;
    const int lane = tid & 63, wv = tid >> 6;
    const int l16 = lane & 15, q = lane >> 4;
    const int row0 = blockIdx.x * 64;
    const int col0 = blockIdx.y * 256;
    const int ar = tid >> 2, ak = (tid & 3) * 8;

    f32x4 acc[4][4] = {};
    float4 pa0, pa1;
    bf16x8 pab;
    bf16x8 pb[4];

    auto loadA = [&](int k0) {
        if (AF32) {
            const float* p = (const float*)Ap + (size_t)(row0 + ar) * K + k0 + ak;
            pa0 = *(const float4*)p;
            pa1 = *(const float4*)(p + 4);
        } else {
            const bf16* p = (const bf16*)Ap + (size_t)(row0 + ar) * K + k0 + ak;
            pab = *(const bf16x8*)p;
        }
    };
    auto loadB = [&](int k0) {
#pragma unroll
        for (int i = 0; i < 4; i++) {
            int idx = tid + i * 256;
            int r = idx >> 2, kk = (idx & 3) * 8;
            pb[i] = *(const bf16x8*)(Bp + (size_t)(col0 + r) * K + k0 + kk);
        }
    };
    auto stage = [&]() {
        if (AF32) {
            bf16x8 v;
            v[0] = (bf16)pa0.x; v[1] = (bf16)pa0.y; v[2] = (bf16)pa0.z; v[3] = (bf16)pa0.w;
            v[4] = (bf16)pa1.x; v[5] = (bf16)pa1.y; v[6] = (bf16)pa1.z; v[7] = (bf16)pa1.w;
            *(bf16x8*)(sA + ar * 40 + ak) = v;
        } else {
            *(bf16x8*)(sA + ar * 40 + ak) = pab;
        }
#pragma unroll
        for (int i = 0; i < 4; i++) {
            int idx = tid + i * 256;
            int r = idx >> 2, kk = (idx & 3) * 8;
            *(bf16x8*)(sB + r * 40 + kk) = pb[i];
        }
    };

    loadA(0);
    loadB(0);
    const int S = K / 32;
    for (int s = 0; s < S; s++) {
        stage();
        __syncthreads();
        if (s + 1 < S) { loadA((s + 1) * 32); loadB((s + 1) * 32); }
        bf16x8 af[4], bfr[4];
#pragma unroll
        for (int tm = 0; tm < 4; tm++)
            af[tm] = *(bf16x8*)(sA + (tm * 16 + l16) * 40 + q * 8);
#pragma unroll
        for (int tn = 0; tn < 4; tn++)
            bfr[tn] = *(bf16x8*)(sB + (wv * 64 + tn * 16 + l16) * 40 + q * 8);
#pragma unroll
        for (int tm = 0; tm < 4; tm++)
#pragma unroll
            for (int tn = 0; tn < 4; tn++)
                acc[tm][tn] = __builtin_amdgcn_mfma_f32_16x16x32_bf16(
                    af[tm], bfr[tn], acc[tm][tn], 0, 0, 0);
        __syncthreads();
    }

#pragma unroll
    for (int tm = 0; tm < 4; tm++)
#pragma unroll
        for (int tn = 0; tn < 4; tn++)
#pragma unroll
            for (int r = 0; r < 4; r++) {
                int row = row0 + tm * 16 + q * 4 + r;
                int col = col0 + wv * 64 + tn * 16 + l16;
                float v = acc[tm][tn][r] + bias[col];
                if (ACT == 1)
                    ((bf16*)Cp)[(size_t)row * NTOT + col] = (bf16)sigf(v);
                else
                    ((float*)Cp)[(size_t)row * NTOT + col] = v;
            }
}

// ---------------------------------------------------------------------------
// Split-K GEMM for the K=4096 x-layer. R7: KS=2 (was 4) -> Cpart round-trip
// halved (25.2 MB), 384 blocks still 1.5/CU.
// ---------------------------------------------------------------------------
template <int K, int CHUNK>
__global__ __launch_bounds__(256) void k_gemm_sk(const float* __restrict__ Ap,
                                                 const bf16* __restrict__ Bp,
                                                 float* __restrict__ Cpart) {
    __shared__ bf16 sA[64 * 40];
    __shared__ bf16 sB[256 * 40];
    const int tid = threadIdx.x;
    const int lane = tid & 63, wv = tid >> 6;
    const int l16 = lane & 15, q = lane >> 4;
    const int row0 = blockIdx.x * 64;
    const int kb = blockIdx.y * CHUNK;
    float* Cp = Cpart + (size_t)blockIdx.y * 12288 * 256;
    const int ar = tid >> 2, ak = (tid & 3) * 8;

    f32x4 acc[4][4] = {};
    float4 pa0, pa1;
    bf16x8 pb[4];

    auto loadA = [&](int k0) {
        const float* p = Ap + (size_t)(row0 + ar) * K + kb + k0 + ak;
        pa0 = *(const float4*)p;
        pa1 = *(const float4*)(p + 4);
    };
    auto loadB = [&](int k0) {
#pragma unroll
        for (int i = 0; i < 4; i++) {
            int idx = tid + i * 256;
            int r = idx >> 2, kk = (idx & 3) * 8;
            pb[i] = *(const bf16x8*)(Bp + (size_t)r * K + kb + k0 + kk);
        }
    };
    auto stage = [&]() {
        bf16x8 v;
        v[0] = (bf16)pa0.x; v[1] = (bf16)pa0.y; v[2] = (bf16)pa0.z; v[3] = (bf16)pa0.w;
        v[4] = (bf16)pa1.x; v[5] = (bf16)pa1.y; v[6] = (bf16)pa1.z; v[7] = (bf16)pa1.w;
        *(bf16x8*)(sA + ar * 40 + ak) = v;
#pragma unroll
        for (int i = 0; i < 4; i++) {
            int idx = tid + i * 256;
            int r = idx >> 2, kk = (idx & 3) * 8;
            *(bf16x8*)(sB + r * 40 + kk) = pb[i];
        }
    };

    loadA(0);
    loadB(0);
    const int S = CHUNK / 32;
    for (int s = 0; s < S; s++) {
        stage();
        __syncthreads();
        if (s + 1 < S) { loadA((s + 1) * 32); loadB((s + 1) * 32); }
        bf16x8 af[4], bfr[4];
#pragma unroll
        for (int tm = 0; tm < 4; tm++)
            af[tm] = *(bf16x8*)(sA + (tm * 16 + l16) * 40 + q * 8);
#pragma unroll
        for (int tn = 0; tn < 4; tn++)
            bfr[tn] = *(bf16x8*)(sB + (wv * 64 + tn * 16 + l16) * 40 + q * 8);
#pragma unroll
        for (int tm = 0; tm < 4; tm++)
#pragma unroll
            for (int tn = 0; tn < 4; tn++)
                acc[tm][tn] = __builtin_amdgcn_mfma_f32_16x16x32_bf16(
                    af[tm], bfr[tn], acc[tm][tn], 0, 0, 0);
        __syncthreads();
    }

#pragma unroll
    for (int tm = 0; tm < 4; tm++)
#pragma unroll
        for (int tn = 0; tn < 4; tn++)
#pragma unroll
            for (int r = 0; r < 4; r++) {
                int row = row0 + tm * 16 + q * 4 + r;
                int col = wv * 64 + tn * 16 + l16;
                Cp[(size_t)row * 256 + col] = acc[tm][tn][r];
            }
}

// Reduce the KS split-K partials + bias + sigmoid -> bf16 t2.
template <int KS>
__global__ __launch_bounds__(256) void k_reduce(const float* __restrict__ Cpart,
                                                const float* __restrict__ bias,
                                                bf16* __restrict__ t2) {
    const size_t STRIDE = (size_t)12288 * 256;
    size_t i = ((size_t)blockIdx.x * 256 + threadIdx.x) * 4;
    f32x4 s = *(const f32x4*)(Cpart + i);
#pragma unroll
    for (int ks = 1; ks < KS; ks++) {
        f32x4 p = *(const f32x4*)(Cpart + ks * STRIDE + i);
        s[0] += p[0]; s[1] += p[1]; s[2] += p[2]; s[3] += p[3];
    }
    int col = (int)(i & 255);
    const float4 b = *(const float4*)(bias + col);
    bf16x4 o;
    o[0] = (bf16)sigf(s[0] + b.x);
    o[1] = (bf16)sigf(s[1] + b.y);
    o[2] = (bf16)sigf(s[2] + b.z);
    o[3] = (bf16)sigf(s[3] + b.w);
    *(bf16x4*)(t2 + i) = o;
}

// ---------------------------------------------------------------------------
// Persistent GRU layer, R7: the xw[t] tile (16 rows x 768 f32 = 48 KB) is
// async-prefetched into LDS via global_load_lds at the START of each step,
// so its HBM/L3 latency hides under the Phase-A MFMAs and the epilogue reads
// LDS (~120 cyc) instead of global (~900 cyc). No VGPRs held by the prefetch
// (fire-and-forget direct-to-LDS) -> no register-pressure change vs the
// R0-proven kernel. The mid-step __syncthreads drains vmcnt -> tile resident.
// Refills are safe: they occur after the end-of-step barrier that orders all
// prior epilogue LDS reads. xwl stride 772 f32: rows 16-B aligned (772%4==0)
// and 4-row lane stride 4*772 % 32 == 16 -> 2 lanes/bank (free, m136).
// ---------------------------------------------------------------------------
__global__ __launch_bounds__(512, 2) void k_gru(const float* __restrict__ xw,   // [12,1024,768]
                                                const bf16* __restrict__ Wpk,   // packed [8][6][8][64][8]
                                                const float* __restrict__ bhh,  // [768]
                                                const float* __restrict__ h0,   // [1024,256]
                                                bf16* __restrict__ hs_out,      // [12,1024,256] or null
                                                float* __restrict__ hfin) {     // [1024,256] or null
    __shared__ bf16 hl[16 * 264];       // 8448 B
    __shared__ float xwl[16 * 772];     // 49408 B; total 57856 B < 64 KB
    const int tid = threadIdx.x, lane = tid & 63, wv = tid >> 6;
    const int l16 = lane & 15, q = lane >> 4;
    const int row0 = blockIdx.x * 16;
    const bf16* wb = Wpk + (size_t)wv * 6 * 8 * 64 * 8;

    float bh[6];
#pragma unroll
    for (int c = 0; c < 6; c++) {
        int g = c >> 1;
        bh[c] = bhh[g * 256 + wv * 32 + (c & 1) * 16 + l16];
    }
    float hreg[2][4];
#pragma unroll
    for (int hc = 0; hc < 2; hc++)
#pragma unroll
        for (int r = 0; r < 4; r++) {
            int row = q * 4 + r, col = wv * 32 + hc * 16 + l16;
            float h = h0[(size_t)(row0 + row) * 256 + col];
            hreg[hc][r] = h;
            hl[row * 264 + col] = (bf16)h;
        }
    __syncthreads();

    for (int t = 0; t < 12; t++) {
        // ---- async prefetch of xw tile t into LDS (wave wv copies its 2 rows,
        //      3 x 1 KB issues per row; 64 lanes x 16 B each) ----
        {
            const float* gbase = xw + ((size_t)t * 1024 + row0) * 768;
#pragma unroll
            for (int rr = 0; rr < 2; rr++) {
                int row = wv * 2 + rr;
#pragma unroll
                for (int i = 0; i < 3; i++) {
                    const float* gp = gbase + (size_t)row * 768 + i * 256 + lane * 4;
                    float* lp = xwl + row * 772 + i * 256;
                    __builtin_amdgcn_global_load_lds(
                        (const __attribute__((address_space(1))) void*)gp,
                        (__attribute__((address_space(3))) void*)lp,
                        16, 0, 0);
                }
            }
        }
        // ---- Phase A: hh = h_{t-1} @ Whh^T (weights streamed, dbuf) ----
        f32x4 acc[6] = {};
        bf16x8 bc[6], bn[6];
#pragma unroll
        for (int c = 0; c < 6; c++)
            bc[c] = *(const bf16x8*)(wb + ((size_t)(c * 8 + 0) * 64 + lane) * 8);
#pragma unroll
        for (int kt = 0; kt < 8; kt++) {
            bf16x8 a = *(bf16x8*)(hl + l16 * 264 + kt * 32 + q * 8);
            if (kt < 7) {
#pragma unroll
                for (int c = 0; c < 6; c++)
                    bn[c] = *(const bf16x8*)(wb + ((size_t)(c * 8 + kt + 1) * 64 + lane) * 8);
            }
#pragma unroll
            for (int c = 0; c < 6; c++)
                acc[c] = __builtin_amdgcn_mfma_f32_16x16x32_bf16(a, bc[c], acc[c], 0, 0, 0);
#pragma unroll
            for (int c = 0; c < 6; c++) bc[c] = bn[c];
        }
        __syncthreads();   // hl reads done; drains vmcnt -> xwl tile resident
        // ---- Epilogue: GRU cell, xw read from LDS ----
#pragma unroll
        for (int hc = 0; hc < 2; hc++)
#pragma unroll
            for (int r = 0; r < 4; r++) {
                int row = q * 4 + r, col = wv * 32 + hc * 16 + l16;
                const float* xb = xwl + row * 772 + col;
                float rv = sigf(xb[0] + acc[hc][r] + bh[hc]);
                float zv = sigf(xb[256] + acc[2 + hc][r] + bh[2 + hc]);
                float nv = tanhf_fast(xb[512] + rv * (acc[4 + hc][r] + bh[4 + hc]));
                float hn = (1.f - zv) * nv + zv * hreg[hc][r];
                hreg[hc][r] = hn;
                bf16 hb = (bf16)hn;
                hl[row * 264 + col] = hb;
                if (hs_out) hs_out[((size_t)t * 1024 + row0 + row) * 256 + col] = hb;
            }
        __syncthreads();   // h_t visible; xwl free for next step's refill
    }
    if (hfin) {
#pragma unroll
        for (int hc = 0; hc < 2; hc++)
#pragma unroll
            for (int r = 0; r < 4; r++) {
                int row = q * 4 + r, col = wv * 32 + hc * 16 + l16;
                hfin[(size_t)(row0 + row) * 256 + col] = hreg[hc][r];
            }
    }
}

// ---------------------------------------------------------------------------
// Final MLP on last hidden state: 256 -> 16 -> 16 -> 1, all sigmoid.
// ---------------------------------------------------------------------------
__global__ __launch_bounds__(256) void k_final(const float* __restrict__ h,
                                               const float* __restrict__ Wf0, const float* __restrict__ bf0,
                                               const float* __restrict__ Wf1, const float* __restrict__ bf1,
                                               const float* __restrict__ Wf2, const float* __restrict__ bf2,
                                               float* __restrict__ out) {
    __shared__ float sh[16 * 257];
    __shared__ float sy0[16 * 17];
    __shared__ float sy1[16 * 17];
    int tid = threadIdx.x;
    int r0 = blockIdx.x * 16;
#pragma unroll
    for (int i = 0; i < 16; i++) {
        int idx = tid + i * 256;
        int rr = idx >> 8, cc = idx & 255;
        sh[rr * 257 + cc] = h[(size_t)(r0 + rr) * 256 + cc];
    }
    __syncthreads();
    int rl = tid >> 4, j = tid & 15;
    float acc = bf0[j];
    for (int k = 0; k < 256; k++) acc += sh[rl * 257 + k] * Wf0[j * 256 + k];
    sy0[rl * 17 + j] = sigf(acc);
    __syncthreads();
    float acc1 = bf1[j];
#pragma unroll
    for (int k = 0; k < 16; k++) acc1 += sy0[rl * 17 + k] * Wf1[j * 16 + k];
    sy1[rl * 17 + j] = sigf(acc1);
    __syncthreads();
    if (tid < 16) {
        float a2 = bf2[0];
#pragma unroll
        for (int k = 0; k < 16; k++) a2 += sy1[tid * 17 + k] * Wf2[k];
        out[r0 + tid] = sigf(a2);
    }
}

extern "C" void kernel_launch(void* const* d_in, const int* in_sizes, int n_in,
                              void* d_out, int out_size, void* d_ws, size_t ws_size,
                              hipStream_t stream) {
    const float* x    = (const float*)d_in[0];
    const float* h0   = (const float*)d_in[1];
    const float* A    = (const float*)d_in[2];
    const float* Wgnn = (const float*)d_in[3];
    const float* bgnn = (const float*)d_in[4];
    const float* Wlin = (const float*)d_in[5];
    const float* blin = (const float*)d_in[6];
    const float* Wih0 = (const float*)d_in[7];
    const float* Whh0 = (const float*)d_in[8];
    const float* bih0 = (const float*)d_in[9];
    const float* bhh0 = (const float*)d_in[10];
    const float* Wih1 = (const float*)d_in[11];
    const float* Whh1 = (const float*)d_in[12];
    const float* bih1 = (const float*)d_in[13];
    const float* bhh1 = (const float*)d_in[14];
    const float* Wf0  = (const float*)d_in[15];
    const float* bf0  = (const float*)d_in[16];
    const float* Wf1  = (const float*)d_in[17];
    const float* bf1  = (const float*)d_in[18];
    const float* Wf2  = (const float*)d_in[19];
    const float* bf2  = (const float*)d_in[20];
    float* out = (float*)d_out;

    char* w = (char*)d_ws;
    bf16* Weff  = (bf16*)w;  w += (size_t)256 * 4096 * 2;
    bf16* WlinB = (bf16*)w;  w += (size_t)256 * 256 * 2;
    bf16* Wih0B = (bf16*)w;  w += (size_t)768 * 256 * 2;
    bf16* Wih1B = (bf16*)w;  w += (size_t)768 * 256 * 2;
    bf16* Wpk0  = (bf16*)w;  w += (size_t)768 * 256 * 2;
    bf16* Wpk1  = (bf16*)w;  w += (size_t)768 * 256 * 2;
    bf16* t2    = (bf16*)w;  w += (size_t)12288 * 256 * 2;
    bf16* t4    = (bf16*)w;  w += (size_t)12288 * 256 * 2;
    // Union region: Cpart (2 x 12288 x 256 f32 = 25.2 MB) is dead before
    // xwb/hs/hfin are first written (xwb 37.7 + hs 6.3 + hfin 1.0 = 45 MB).
    float* Cpart = (float*)w;
    float* xwb  = (float*)w;
    bf16*  hs   = (bf16*)(w + (size_t)12288 * 768 * 4);
    float* hfin = (float*)(w + (size_t)12288 * 768 * 4 + (size_t)12288 * 256 * 2);
    w += (size_t)4 * 12288 * 256 * 4;
    (void)ws_size;

    k_weff<<<dim3(16, 32), 256, 0, stream>>>(A, Wgnn, Weff);
    k_prep<<<dim3(1984), 256, 0, stream>>>(Wlin, WlinB, Wih0, Wih0B, Wih1, Wih1B,
                                           Whh0, Wpk0, Whh1, Wpk1);

    // t2 = sigmoid(x @ Weff^T + b_gnn): M=12288, K=4096 split 2 ways
    k_gemm_sk<4096, 2048><<<dim3(192, 2), 256, 0, stream>>>(x, Weff, Cpart);
    k_reduce<2><<<dim3(3072), 256, 0, stream>>>(Cpart, bgnn, t2);
    // t4 = sigmoid(t2 @ Wlin^T + b_lin)
    k_gemm<256, 256, 1, false><<<dim3(192, 1), 256, 0, stream>>>(t2, WlinB, blin, t4);
    // xW0 = t4 @ Wih0^T + bih0  -> [12288, 768] f32
    k_gemm<256, 768, 0, false><<<dim3(192, 3), 256, 0, stream>>>(t4, Wih0B, bih0, xwb);
    // GRU layer 0 -> hs (bf16, all timesteps)
    k_gru<<<dim3(64), 512, 0, stream>>>(xwb, Wpk0, bhh0, h0, hs, nullptr);
    // xW1 = hs @ Wih1^T + bih1 (reuses xwb)
    k_gemm<256, 768, 0, false><<<dim3(192, 3), 256, 0, stream>>>(hs, Wih1B, bih1, xwb);
    // GRU layer 1 -> final hidden only
    k_gru<<<dim3(64), 512, 0, stream>>>(xwb, Wpk1, bhh1, h0 + (size_t)1024 * 256, nullptr, hfin);
    // final MLP
    k_final<<<dim3(64), 256, 0, stream>>>(hfin, Wf0, bf0, Wf1, bf1, Wf2, bf2, out);
}

// Round 8
// 554.599 us; speedup vs baseline: 1.4637x; 1.0047x over previous
//
#include <hip/hip_runtime.h>
#include <hip/hip_bf16.h>

typedef __bf16 bf16;
typedef __bf16 bf16x4 __attribute__((ext_vector_type(4)));
typedef __bf16 bf16x8 __attribute__((ext_vector_type(8)));
typedef float  f32x4  __attribute__((ext_vector_type(4)));

__device__ __forceinline__ float sigf(float x) { return 1.f / (1.f + __expf(-x)); }
// tanh(x) = 1 - 2/(e^{2x}+1): safe at both infinities (no inf/inf NaN)
__device__ __forceinline__ float tanhf_fast(float x) { return 1.f - 2.f / (1.f + __expf(2.f * x)); }

// ---------------------------------------------------------------------------
// Journal: R1-R5 fused-GRU attempts spilled (~50 MB phantom traffic) -> split
// structure kept. R7: GRU xw LDS-prefetch + weff parallelism = 557 us, but
// KS=2 split-K regressed the x-GEMM to 125 us (1.5 blocks/CU, latency-bound,
// occupancy 14%). R8: replace split-K + reduce with an N-tiled one-pass GEMM:
// grid (192,4) = 768 blocks (3/CU), 64x64 tiles, BK=64, fused
// bias+sigmoid+bf16 epilogue. Same-row col-blocks are 192 apart in linear id
// (192%8==0 -> same XCD) so x slices are fetched from HBM once per row.
// ---------------------------------------------------------------------------

// ---------------------------------------------------------------------------
// W_eff[d][n] = sum_m W_gnn[d][m] * A[m][n]; A is I + symmetric 9-pt stencil,
// values read from the real A input (only the sparsity pattern is assumed).
// ---------------------------------------------------------------------------
__global__ __launch_bounds__(256) void k_weff(const float* __restrict__ A,
                                              const float* __restrict__ Wg,
                                              bf16* __restrict__ Weff) {
    int n = blockIdx.x * 256 + threadIdx.x;
    const int offs[9] = {0, -1, 1, 64, -64, 63, 65, -65, -63};
    float w[9];
    int   m[9];
#pragma unroll
    for (int j = 0; j < 9; j++) {
        int mm = n + offs[j];
        bool ok = (mm >= 0 && mm < 4096);
        m[j] = ok ? mm : 0;
        w[j] = ok ? A[(size_t)n * 4096 + mm] : 0.f;
    }
    int d0 = blockIdx.y * 8;
    for (int d = d0; d < d0 + 8; d++) {
        const float* wr = Wg + (size_t)d * 4096;
        float acc = 0.f;
#pragma unroll
        for (int j = 0; j < 9; j++) acc += w[j] * wr[m[j]];
        Weff[(size_t)d * 4096 + n] = (bf16)acc;
    }
}

// ---------------------------------------------------------------------------
// Merged prologue: 3 f32->bf16 weight conversions + 2 MFMA-order packs.
// Pack layout: flat frag id fl = ((wv*6 + c)*8 + kt)*64 + lane, 8 elems each.
// ---------------------------------------------------------------------------
__device__ __forceinline__ void prep_conv(const float* __restrict__ a,
                                          bf16* __restrict__ o, int blk) {
    int i = blk * 256 + threadIdx.x;
    o[i] = (bf16)a[i];
}

__device__ __forceinline__ void prep_pack(const float* __restrict__ W,
                                          bf16* __restrict__ out, int blk) {
    int fl = blk * 256 + threadIdx.x;             // 0 .. 24575
    int lane = fl & 63;
    int kt = (fl >> 6) & 7;
    int c  = (fl >> 9) % 6;
    int wv = (fl >> 9) / 6;
    int l16 = lane & 15, q = lane >> 4;
    int g = c >> 1;
    int wr = g * 256 + wv * 32 + (c & 1) * 16 + l16;
    const float* p = W + (size_t)wr * 256 + kt * 32 + q * 8;
    float4 f0 = *(const float4*)p, f1 = *(const float4*)(p + 4);
    bf16x8 v;
    v[0] = (bf16)f0.x; v[1] = (bf16)f0.y; v[2] = (bf16)f0.z; v[3] = (bf16)f0.w;
    v[4] = (bf16)f1.x; v[5] = (bf16)f1.y; v[6] = (bf16)f1.z; v[7] = (bf16)f1.w;
    *(bf16x8*)(out + (size_t)fl * 8) = v;
}

__global__ __launch_bounds__(256) void k_prep(const float* __restrict__ Wlin, bf16* __restrict__ WlinB,
                                              const float* __restrict__ Wih0, bf16* __restrict__ Wih0B,
                                              const float* __restrict__ Wih1, bf16* __restrict__ Wih1B,
                                              const float* __restrict__ Whh0, bf16* __restrict__ Wpk0,
                                              const float* __restrict__ Whh1, bf16* __restrict__ Wpk1) {
    int b = blockIdx.x;
    if (b < 256)        prep_conv(Wlin, WlinB, b);            // 256*256   = 65536
    else if (b < 1024)  prep_conv(Wih0, Wih0B, b - 256);      // 768*256   = 196608
    else if (b < 1792)  prep_conv(Wih1, Wih1B, b - 1024);     // 768*256   = 196608
    else if (b < 1888)  prep_pack(Whh0, Wpk0, b - 1792);      // 96 blocks
    else                prep_pack(Whh1, Wpk1, b - 1888);      // 96 blocks
}

// ---------------------------------------------------------------------------
// One-pass x-layer GEMM: t2 = sigmoid(x[12288,4096] @ Weff[256,4096]^T + b),
// bf16 out. Grid (192,4): 64x64 tile per block, BK=64 (64 iters), 4 waves,
// wave-tile 16x64. Replaces split-K + Cpart round-trip + k_reduce.
// ---------------------------------------------------------------------------
__global__ __launch_bounds__(256) void k_gemm_x(const float* __restrict__ Ap,
                                                const bf16* __restrict__ Bp,
                                                const float* __restrict__ bias,
                                                bf16* __restrict__ Cp) {
    __shared__ bf16 sA[64 * 72];   // 9216 B, rows 144 B (16-B aligned)
    __shared__ bf16 sB[64 * 72];   // 9216 B
    const int tid = threadIdx.x;
    const int lane = tid & 63, wv = tid >> 6;
    const int l16 = lane & 15, q = lane >> 4;
    const int row0 = blockIdx.x * 64;
    const int col0 = blockIdx.y * 64;
    const int ar = tid >> 2, ak = (tid & 3) * 16;   // 64 rows x 64 K coverage

    f32x4 acc[4] = {};
    float4 pa0, pa1, pa2, pa3;
    bf16x8 pb0, pb1;

    auto loadA = [&](int k0) {
        const float* p = Ap + (size_t)(row0 + ar) * 4096 + k0 + ak;
        pa0 = *(const float4*)p;
        pa1 = *(const float4*)(p + 4);
        pa2 = *(const float4*)(p + 8);
        pa3 = *(const float4*)(p + 12);
    };
    auto loadB = [&](int k0) {
        const bf16* p = Bp + (size_t)(col0 + ar) * 4096 + k0 + ak;
        pb0 = *(const bf16x8*)p;
        pb1 = *(const bf16x8*)(p + 8);
    };
    auto stage = [&]() {
        bf16x8 v0, v1;
        v0[0] = (bf16)pa0.x; v0[1] = (bf16)pa0.y; v0[2] = (bf16)pa0.z; v0[3] = (bf16)pa0.w;
        v0[4] = (bf16)pa1.x; v0[5] = (bf16)pa1.y; v0[6] = (bf16)pa1.z; v0[7] = (bf16)pa1.w;
        v1[0] = (bf16)pa2.x; v1[1] = (bf16)pa2.y; v1[2] = (bf16)pa2.z; v1[3] = (bf16)pa2.w;
        v1[4] = (bf16)pa3.x; v1[5] = (bf16)pa3.y; v1[6] = (bf16)pa3.z; v1[7] = (bf16)pa3.w;
        *(bf16x8*)(sA + ar * 72 + ak) = v0;
        *(bf16x8*)(sA + ar * 72 + ak + 8) = v1;
        *(bf16x8*)(sB + ar * 72 + ak) = pb0;
        *(bf16x8*)(sB + ar * 72 + ak + 8) = pb1;
    };

    loadA(0);
    loadB(0);
    for (int s = 0; s < 64; s++) {
        stage();
        __syncthreads();
        if (s + 1 < 64) { loadA((s + 1) * 64); loadB((s + 1) * 64); }
#pragma unroll
        for (int kk = 0; kk < 2; kk++) {
            bf16x8 a = *(bf16x8*)(sA + (wv * 16 + l16) * 72 + kk * 32 + q * 8);
#pragma unroll
            for (int tn = 0; tn < 4; tn++) {
                bf16x8 b = *(bf16x8*)(sB + (tn * 16 + l16) * 72 + kk * 32 + q * 8);
                acc[tn] = __builtin_amdgcn_mfma_f32_16x16x32_bf16(a, b, acc[tn], 0, 0, 0);
            }
        }
        __syncthreads();
    }

#pragma unroll
    for (int tn = 0; tn < 4; tn++)
#pragma unroll
        for (int r = 0; r < 4; r++) {
            int row = row0 + wv * 16 + q * 4 + r;
            int col = col0 + tn * 16 + l16;
            Cp[(size_t)row * 256 + col] = (bf16)sigf(acc[tn][r] + bias[col]);
        }
}

// ---------------------------------------------------------------------------
// GEMM: C = act(A[M,K] @ B[NTOT,K]^T + bias).  Block tile 64x256, 4 waves,
// wave-tile 64x64.  ACT: 0 = +bias f32 out; 1 = +bias sigmoid bf16 out.
// ---------------------------------------------------------------------------
template <int K, int NTOT, int ACT, bool AF32>
__global__ __launch_bounds__(256) void k_gemm(const void* __restrict__ Ap,
                                              const bf16* __restrict__ Bp,
                                              const float* __restrict__ bias,
                                              void* __restrict__ Cp) {
    __shared__ bf16 sA[64 * 40];
    __shared__ bf16 sB[256 * 40];
    const int tid = threadIdx.x;
    const int lane = tid & 63, wv = tid >> 6;
    const int l16 = lane & 15, q = lane >> 4;
    const int row0 = blockIdx.x * 64;
    const int col0 = blockIdx.y * 256;
    const int ar = tid >> 2, ak = (tid & 3) * 8;

    f32x4 acc[4][4] = {};
    float4 pa0, pa1;
    bf16x8 pab;
    bf16x8 pb[4];

    auto loadA = [&](int k0) {
        if (AF32) {
            const float* p = (const float*)Ap + (size_t)(row0 + ar) * K + k0 + ak;
            pa0 = *(const float4*)p;
            pa1 = *(const float4*)(p + 4);
        } else {
            const bf16* p = (const bf16*)Ap + (size_t)(row0 + ar) * K + k0 + ak;
            pab = *(const bf16x8*)p;
        }
    };
    auto loadB = [&](int k0) {
#pragma unroll
        for (int i = 0; i < 4; i++) {
            int idx = tid + i * 256;
            int r = idx >> 2, kk = (idx & 3) * 8;
            pb[i] = *(const bf16x8*)(Bp + (size_t)(col0 + r) * K + k0 + kk);
        }
    };
    auto stage = [&]() {
        if (AF32) {
            bf16x8 v;
            v[0] = (bf16)pa0.x; v[1] = (bf16)pa0.y; v[2] = (bf16)pa0.z; v[3] = (bf16)pa0.w;
            v[4] = (bf16)pa1.x; v[5] = (bf16)pa1.y; v[6] = (bf16)pa1.z; v[7] = (bf16)pa1.w;
            *(bf16x8*)(sA + ar * 40 + ak) = v;
        } else {
            *(bf16x8*)(sA + ar * 40 + ak) = pab;
        }
#pragma unroll
        for (int i = 0; i < 4; i++) {
            int idx = tid + i * 256;
            int r = idx >> 2, kk = (idx & 3) * 8;
            *(bf16x8*)(sB + r * 40 + kk) = pb[i];
        }
    };

    loadA(0);
    loadB(0);
    const int S = K / 32;
    for (int s = 0; s < S; s++) {
        stage();
        __syncthreads();
        if (s + 1 < S) { loadA((s + 1) * 32); loadB((s + 1) * 32); }
        bf16x8 af[4], bfr[4];
#pragma unroll
        for (int tm = 0; tm < 4; tm++)
            af[tm] = *(bf16x8*)(sA + (tm * 16 + l16) * 40 + q * 8);
#pragma unroll
        for (int tn = 0; tn < 4; tn++)
            bfr[tn] = *(bf16x8*)(sB + (wv * 64 + tn * 16 + l16) * 40 + q * 8);
#pragma unroll
        for (int tm = 0; tm < 4; tm++)
#pragma unroll
            for (int tn = 0; tn < 4; tn++)
                acc[tm][tn] = __builtin_amdgcn_mfma_f32_16x16x32_bf16(
                    af[tm], bfr[tn], acc[tm][tn], 0, 0, 0);
        __syncthreads();
    }

#pragma unroll
    for (int tm = 0; tm < 4; tm++)
#pragma unroll
        for (int tn = 0; tn < 4; tn++)
#pragma unroll
            for (int r = 0; r < 4; r++) {
                int row = row0 + tm * 16 + q * 4 + r;
                int col = col0 + wv * 64 + tn * 16 + l16;
                float v = acc[tm][tn][r] + bias[col];
                if (ACT == 1)
                    ((bf16*)Cp)[(size_t)row * NTOT + col] = (bf16)sigf(v);
                else
                    ((float*)Cp)[(size_t)row * NTOT + col] = v;
            }
}

// ---------------------------------------------------------------------------
// Persistent GRU layer (R7-proven): xw[t] tile async-prefetched into LDS via
// global_load_lds at step start (no VGPRs held -> no spill); latency hides
// under the Phase-A MFMAs; epilogue reads LDS. xwl stride 772 f32.
// ---------------------------------------------------------------------------
__global__ __launch_bounds__(512, 2) void k_gru(const float* __restrict__ xw,   // [12,1024,768]
                                                const bf16* __restrict__ Wpk,   // packed [8][6][8][64][8]
                                                const float* __restrict__ bhh,  // [768]
                                                const float* __restrict__ h0,   // [1024,256]
                                                bf16* __restrict__ hs_out,      // [12,1024,256] or null
                                                float* __restrict__ hfin) {     // [1024,256] or null
    __shared__ bf16 hl[16 * 264];       // 8448 B
    __shared__ float xwl[16 * 772];     // 49408 B; total 57856 B < 64 KB
    const int tid = threadIdx.x, lane = tid & 63, wv = tid >> 6;
    const int l16 = lane & 15, q = lane >> 4;
    const int row0 = blockIdx.x * 16;
    const bf16* wb = Wpk + (size_t)wv * 6 * 8 * 64 * 8;

    float bh[6];
#pragma unroll
    for (int c = 0; c < 6; c++) {
        int g = c >> 1;
        bh[c] = bhh[g * 256 + wv * 32 + (c & 1) * 16 + l16];
    }
    float hreg[2][4];
#pragma unroll
    for (int hc = 0; hc < 2; hc++)
#pragma unroll
        for (int r = 0; r < 4; r++) {
            int row = q * 4 + r, col = wv * 32 + hc * 16 + l16;
            float h = h0[(size_t)(row0 + row) * 256 + col];
            hreg[hc][r] = h;
            hl[row * 264 + col] = (bf16)h;
        }
    __syncthreads();

    for (int t = 0; t < 12; t++) {
        // ---- async prefetch of xw tile t into LDS ----
        {
            const float* gbase = xw + ((size_t)t * 1024 + row0) * 768;
#pragma unroll
            for (int rr = 0; rr < 2; rr++) {
                int row = wv * 2 + rr;
#pragma unroll
                for (int i = 0; i < 3; i++) {
                    const float* gp = gbase + (size_t)row * 768 + i * 256 + lane * 4;
                    float* lp = xwl + row * 772 + i * 256;
                    __builtin_amdgcn_global_load_lds(
                        (const __attribute__((address_space(1))) void*)gp,
                        (__attribute__((address_space(3))) void*)lp,
                        16, 0, 0);
                }
            }
        }
        // ---- Phase A: hh = h_{t-1} @ Whh^T (weights streamed, dbuf) ----
        f32x4 acc[6] = {};
        bf16x8 bc[6], bn[6];
#pragma unroll
        for (int c = 0; c < 6; c++)
            bc[c] = *(const bf16x8*)(wb + ((size_t)(c * 8 + 0) * 64 + lane) * 8);
#pragma unroll
        for (int kt = 0; kt < 8; kt++) {
            bf16x8 a = *(bf16x8*)(hl + l16 * 264 + kt * 32 + q * 8);
            if (kt < 7) {
#pragma unroll
                for (int c = 0; c < 6; c++)
                    bn[c] = *(const bf16x8*)(wb + ((size_t)(c * 8 + kt + 1) * 64 + lane) * 8);
            }
#pragma unroll
            for (int c = 0; c < 6; c++)
                acc[c] = __builtin_amdgcn_mfma_f32_16x16x32_bf16(a, bc[c], acc[c], 0, 0, 0);
#pragma unroll
            for (int c = 0; c < 6; c++) bc[c] = bn[c];
        }
        __syncthreads();   // hl reads done; drains vmcnt -> xwl tile resident
        // ---- Epilogue: GRU cell, xw read from LDS ----
#pragma unroll
        for (int hc = 0; hc < 2; hc++)
#pragma unroll
            for (int r = 0; r < 4; r++) {
                int row = q * 4 + r, col = wv * 32 + hc * 16 + l16;
                const float* xb = xwl + row * 772 + col;
                float rv = sigf(xb[0] + acc[hc][r] + bh[hc]);
                float zv = sigf(xb[256] + acc[2 + hc][r] + bh[2 + hc]);
                float nv = tanhf_fast(xb[512] + rv * (acc[4 + hc][r] + bh[4 + hc]));
                float hn = (1.f - zv) * nv + zv * hreg[hc][r];
                hreg[hc][r] = hn;
                bf16 hb = (bf16)hn;
                hl[row * 264 + col] = hb;
                if (hs_out) hs_out[((size_t)t * 1024 + row0 + row) * 256 + col] = hb;
            }
        __syncthreads();   // h_t visible; xwl free for next step's refill
    }
    if (hfin) {
#pragma unroll
        for (int hc = 0; hc < 2; hc++)
#pragma unroll
            for (int r = 0; r < 4; r++) {
                int row = q * 4 + r, col = wv * 32 + hc * 16 + l16;
                hfin[(size_t)(row0 + row) * 256 + col] = hreg[hc][r];
            }
    }
}

// ---------------------------------------------------------------------------
// Final MLP on last hidden state: 256 -> 16 -> 16 -> 1, all sigmoid.
// ---------------------------------------------------------------------------
__global__ __launch_bounds__(256) void k_final(const float* __restrict__ h,
                                               const float* __restrict__ Wf0, const float* __restrict__ bf0,
                                               const float* __restrict__ Wf1, const float* __restrict__ bf1,
                                               const float* __restrict__ Wf2, const float* __restrict__ bf2,
                                               float* __restrict__ out) {
    __shared__ float sh[16 * 257];
    __shared__ float sy0[16 * 17];
    __shared__ float sy1[16 * 17];
    int tid = threadIdx.x;
    int r0 = blockIdx.x * 16;
#pragma unroll
    for (int i = 0; i < 16; i++) {
        int idx = tid + i * 256;
        int rr = idx >> 8, cc = idx & 255;
        sh[rr * 257 + cc] = h[(size_t)(r0 + rr) * 256 + cc];
    }
    __syncthreads();
    int rl = tid >> 4, j = tid & 15;
    float acc = bf0[j];
    for (int k = 0; k < 256; k++) acc += sh[rl * 257 + k] * Wf0[j * 256 + k];
    sy0[rl * 17 + j] = sigf(acc);
    __syncthreads();
    float acc1 = bf1[j];
#pragma unroll
    for (int k = 0; k < 16; k++) acc1 += sy0[rl * 17 + k] * Wf1[j * 16 + k];
    sy1[rl * 17 + j] = sigf(acc1);
    __syncthreads();
    if (tid < 16) {
        float a2 = bf2[0];
#pragma unroll
        for (int k = 0; k < 16; k++) a2 += sy1[tid * 17 + k] * Wf2[k];
        out[r0 + tid] = sigf(a2);
    }
}

extern "C" void kernel_launch(void* const* d_in, const int* in_sizes, int n_in,
                              void* d_out, int out_size, void* d_ws, size_t ws_size,
                              hipStream_t stream) {
    const float* x    = (const float*)d_in[0];
    const float* h0   = (const float*)d_in[1];
    const float* A    = (const float*)d_in[2];
    const float* Wgnn = (const float*)d_in[3];
    const float* bgnn = (const float*)d_in[4];
    const float* Wlin = (const float*)d_in[5];
    const float* blin = (const float*)d_in[6];
    const float* Wih0 = (const float*)d_in[7];
    const float* Whh0 = (const float*)d_in[8];
    const float* bih0 = (const float*)d_in[9];
    const float* bhh0 = (const float*)d_in[10];
    const float* Wih1 = (const float*)d_in[11];
    const float* Whh1 = (const float*)d_in[12];
    const float* bih1 = (const float*)d_in[13];
    const float* bhh1 = (const float*)d_in[14];
    const float* Wf0  = (const float*)d_in[15];
    const float* bf0  = (const float*)d_in[16];
    const float* Wf1  = (const float*)d_in[17];
    const float* bf1  = (const float*)d_in[18];
    const float* Wf2  = (const float*)d_in[19];
    const float* bf2  = (const float*)d_in[20];
    float* out = (float*)d_out;

    char* w = (char*)d_ws;
    bf16* Weff  = (bf16*)w;  w += (size_t)256 * 4096 * 2;
    bf16* WlinB = (bf16*)w;  w += (size_t)256 * 256 * 2;
    bf16* Wih0B = (bf16*)w;  w += (size_t)768 * 256 * 2;
    bf16* Wih1B = (bf16*)w;  w += (size_t)768 * 256 * 2;
    bf16* Wpk0  = (bf16*)w;  w += (size_t)768 * 256 * 2;
    bf16* Wpk1  = (bf16*)w;  w += (size_t)768 * 256 * 2;
    bf16* t2    = (bf16*)w;  w += (size_t)12288 * 256 * 2;
    bf16* t4    = (bf16*)w;  w += (size_t)12288 * 256 * 2;
    // xwb 37.7 MB + hs 6.3 MB + hfin 1.0 MB (Cpart no longer exists).
    float* xwb  = (float*)w;
    bf16*  hs   = (bf16*)(w + (size_t)12288 * 768 * 4);
    float* hfin = (float*)(w + (size_t)12288 * 768 * 4 + (size_t)12288 * 256 * 2);
    w += (size_t)4 * 12288 * 256 * 4;
    (void)ws_size;

    k_weff<<<dim3(16, 32), 256, 0, stream>>>(A, Wgnn, Weff);
    k_prep<<<dim3(1984), 256, 0, stream>>>(Wlin, WlinB, Wih0, Wih0B, Wih1, Wih1B,
                                           Whh0, Wpk0, Whh1, Wpk1);

    // t2 = sigmoid(x @ Weff^T + b_gnn): one pass, N-tiled, fused epilogue
    k_gemm_x<<<dim3(192, 4), 256, 0, stream>>>(x, Weff, bgnn, t2);
    // t4 = sigmoid(t2 @ Wlin^T + b_lin)
    k_gemm<256, 256, 1, false><<<dim3(192, 1), 256, 0, stream>>>(t2, WlinB, blin, t4);
    // xW0 = t4 @ Wih0^T + bih0  -> [12288, 768] f32
    k_gemm<256, 768, 0, false><<<dim3(192, 3), 256, 0, stream>>>(t4, Wih0B, bih0, xwb);
    // GRU layer 0 -> hs (bf16, all timesteps)
    k_gru<<<dim3(64), 512, 0, stream>>>(xwb, Wpk0, bhh0, h0, hs, nullptr);
    // xW1 = hs @ Wih1^T + bih1 (reuses xwb)
    k_gemm<256, 768, 0, false><<<dim3(192, 3), 256, 0, stream>>>(hs, Wih1B, bih1, xwb);
    // GRU layer 1 -> final hidden only
    k_gru<<<dim3(64), 512, 0, stream>>>(xwb, Wpk1, bhh1, h0 + (size_t)1024 * 256, nullptr, hfin);
    // final MLP
    k_final<<<dim3(64), 256, 0, stream>>>(hfin, Wf0, bf0, Wf1, bf1, Wf2, bf2, out);
}